// Round 11
// baseline (15895.587 us; speedup 1.0000x reference)
//
#include <hip/hip_runtime.h>
#include <cstdint>
#include <cstddef>

constexpr int T_STEPS = 200;
constexpr int BATCH   = 2048;
constexpr int E_DIM   = 256;
constexpr int H_DIM   = 512;
constexpr int P0_DIM  = 256;
constexpr int P1_DIM  = 128;
constexpr float ALPHA = 0.3f;

typedef __attribute__((ext_vector_type(8))) _Float16 f16x8;
typedef __attribute__((ext_vector_type(4))) float f32x4;

__device__ __forceinline__ float sigmoidf_(float x){ return 1.0f/(1.0f+expf(-x)); }

__device__ __forceinline__ unsigned short f2h(float f){
    union { _Float16 h; unsigned short u; } v;
    v.h = (_Float16)f;                 // v_cvt_f16_f32, RNE
    return v.u;
}

// ---------------------------------------------------------------------------
// Fragment layouts (halves):
//  a-frag tensor (M x K): Af[rg][kb][lane][8],  rg=row/16, kb=k/32,
//     lane=lq*16+lr holds A[rg*16+lr][kb*32+lq*8+e].
//  b-frag tensor (N x K): Bf[cg][kb][lane][8],  cg=col/16,
//     lane holds B[k=kb*32+lq*8+e][cg*16+lr].
//  A wave loads one frag = 64 lanes x 16B = contiguous 1KB (dwordx4/lane).
// ---------------------------------------------------------------------------
#define AFRAG(p, rg, NKB, kb) (*(const f16x8*)((p) + (((size_t)(rg)*(NKB) + (kb))*64 + lane)*8))
#define BFRAG(p, cg, NKB, kb) (*(const f16x8*)((p) + (((size_t)(cg)*(NKB) + (kb))*64 + lane)*8))

// ---------------------------------------------------------------------------
// Fused stream kernel: 512 blocks = 32 brow-groups x 16 h-groups.
// LDS-free GEMM (direct frag loads); LDS only for the cell epilogue.
// mode 0 (click): a1=extraH(Hc@Ws0), a2=extraV(Hv@Ws1); writes sc, Hcf_new.
// mode 1 (conv):  a1=extraV(Hv@Ws2), a2=extraH(Hc@Ws3); writes sv, hv32, Hvf_new.
// ---------------------------------------------------------------------------
__global__ __launch_bounds__(256, 2) void k_fused(
    const unsigned short* __restrict__ Xf,    // a-frag [128][8][64][8]
    const unsigned short* __restrict__ AHf,   // a-frag [128][16][64][8]
    const unsigned short* __restrict__ AVf,   // a-frag [128][16][64][8]
    const unsigned short* __restrict__ Wgf,   // b-frag [128cg][24][64][8]
    const float* __restrict__ bias,           // [4][512] z-major
    const unsigned short* __restrict__ WsHf,  // b-frag [32cg][16][64][8]
    const unsigned short* __restrict__ WsVf,  // b-frag [32cg][16][64][8]
    const float* __restrict__ g,
    float* __restrict__ sstate, float* __restrict__ Hv32,
    unsigned short* __restrict__ Hnewf,
    const int mode)
{
    __shared__ __align__(16) char lds[50688];
    const int tid = threadIdx.x;
    const int lane = tid & 63, wid = tid >> 6;
    const int wr = wid >> 1, wc = wid & 1;
    const int lr = lane & 15, lq = lane >> 4;

    // XCD-bijective swizzle (r10-verified)
    const int id = blockIdx.x;
    const int virt = ((id & 7) << 6) | (id >> 3);
    const int hgrp = virt >> 5;
    const int brow = (virt & 31) * 64;
    const int h0   = hgrp * 32;
    const int rgb  = brow >> 4;

    f32x4 accg[2][4], acceH[2], acceV[2];
#pragma unroll
    for (int m = 0; m < 2; ++m){
        f32x4 z = {0.f,0.f,0.f,0.f};
#pragma unroll
        for (int n = 0; n < 4; ++n) accg[m][n] = z;
        acceH[m] = z; acceV[m] = z;
    }

    // ---- gates, X part: kbg 0..7 ----
    for (int kb = 0; kb < 8; ++kb){
        f16x8 a[2];
#pragma unroll
        for (int m = 0; m < 2; ++m) a[m] = AFRAG(Xf, rgb + wr*2 + m, 8, kb);
#pragma unroll
        for (int n = 0; n < 4; ++n){
            f16x8 b = BFRAG(Wgf, hgrp*8 + wc*4 + n, 24, kb);
#pragma unroll
            for (int m = 0; m < 2; ++m)
                accg[m][n] = __builtin_amdgcn_mfma_f32_16x16x32_f16(a[m], b, accg[m][n], 0,0,0);
        }
    }
    // ---- gates H part (kbg 8..23) + extraH (kb 0..15), shared a-frags ----
    for (int kb = 0; kb < 16; ++kb){
        f16x8 a[2];
#pragma unroll
        for (int m = 0; m < 2; ++m) a[m] = AFRAG(AHf, rgb + wr*2 + m, 16, kb);
#pragma unroll
        for (int n = 0; n < 4; ++n){
            f16x8 b = BFRAG(Wgf, hgrp*8 + wc*4 + n, 24, 8 + kb);
#pragma unroll
            for (int m = 0; m < 2; ++m)
                accg[m][n] = __builtin_amdgcn_mfma_f32_16x16x32_f16(a[m], b, accg[m][n], 0,0,0);
        }
        f16x8 bx = BFRAG(WsHf, hgrp*2 + wc, 16, kb);
#pragma unroll
        for (int m = 0; m < 2; ++m)
            acceH[m] = __builtin_amdgcn_mfma_f32_16x16x32_f16(a[m], bx, acceH[m], 0,0,0);
    }
    // ---- extraV: kb 0..15 ----
    for (int kb = 0; kb < 16; ++kb){
        f16x8 a[2];
#pragma unroll
        for (int m = 0; m < 2; ++m) a[m] = AFRAG(AVf, rgb + wr*2 + m, 16, kb);
        f16x8 bx = BFRAG(WsVf, hgrp*2 + wc, 16, kb);
#pragma unroll
        for (int m = 0; m < 2; ++m)
            acceV[m] = __builtin_amdgcn_mfma_f32_16x16x32_f16(a[m], bx, acceV[m], 0,0,0);
    }

    // ---- epilogue: gates (activated) + extras (raw) -> LDS (padded) ----
    float* ldsG  = (float*)lds;               // [64][132] fp32
    float* ldsEH = (float*)(lds + 33792);     // [64][33]
    float* ldsEV = (float*)(lds + 42240);     // [64][33]
#pragma unroll
    for (int m = 0; m < 2; ++m){
#pragma unroll
        for (int n = 0; n < 4; ++n){
            const int col = wc*64 + n*16 + lr;          // z*32 + hl
            const int z = col >> 5, hl = col & 31;
            const float bs = bias[z*H_DIM + h0 + hl];
#pragma unroll
            for (int r = 0; r < 4; ++r){
                const int row = wr*32 + m*16 + lq*4 + r;
                float v = accg[m][n][r] + bs;
                v = (z < 3) ? sigmoidf_(v) : tanhf(v);
                ldsG[row*132 + col] = v;
            }
        }
    }
#pragma unroll
    for (int m = 0; m < 2; ++m){
        const int col = wc*16 + lr;
#pragma unroll
        for (int r = 0; r < 4; ++r){
            const int row = wr*32 + m*16 + lq*4 + r;
            ldsEH[row*33 + col] = acceH[m][r];
            ldsEV[row*33 + col] = acceV[m][r];
        }
    }
    __syncthreads();

    // ---- inline cell: 256 threads x 8 elems (r10-verified math) ----
    const int crow = tid >> 2, lqq = tid & 3, ch = lqq * 8;
    const int grow = brow + crow;
    const float gv = g[grow];
    const size_t gbase = (size_t)grow*H_DIM + h0 + ch;
    union U4 { float4 v; float s[4]; };
    U4 sv0, sv1, hv0, hv1;
    sv0.v = *(const float4*)&sstate[gbase];
    sv1.v = *(const float4*)&sstate[gbase + 4];
    if (mode == 1){
        hv0.v = *(const float4*)&Hv32[gbase];
        hv1.v = *(const float4*)&Hv32[gbase + 4];
    }
    U4 sn0, sn1, hn0, hn1;
    union { unsigned short u[8]; f16x8 v; } hh;
#pragma unroll
    for (int e = 0; e < 8; ++e){
        const int hc = ch + e;
        const float f_ = ldsG[crow*132 + hc];
        const float i_ = ldsG[crow*132 + 32 + hc];
        const float o_ = ldsG[crow*132 + 64 + hc];
        const float q_ = ldsG[crow*132 + 96 + hc];
        const float eh = ldsEH[crow*33 + hc];
        const float ev = ldsEV[crow*33 + hc];
        const float a1 = (mode == 0) ? eh : ev;
        const float a2 = (mode == 0) ? ev : eh;
        const float svo = (e < 4) ? sv0.s[e] : sv1.s[e-4];
        float s, hval;
        if (mode == 0){
            const float shat = tanhf((1.0f - gv)*a1 + gv*a2);
            s = shat + i_*q_ + (1.0f - gv)*(f_*svo);
            hval = o_ * tanhf(s);
        } else {
            const float shat = tanhf(a1 + gv*a2);
            s = shat + (1.0f - gv)*svo + gv*(f_*svo + i_*q_);
            const float hvo = (e < 4) ? hv0.s[e] : hv1.s[e-4];
            hval = (1.0f - gv)*hvo + gv*(o_*tanhf(s));
            if (e < 4) hn0.s[e] = hval; else hn1.s[e-4] = hval;
        }
        if (e < 4) sn0.s[e] = s; else sn1.s[e-4] = s;
        hh.u[e] = f2h(hval);
    }
    *(float4*)&sstate[gbase]     = sn0.v;
    *(float4*)&sstate[gbase + 4] = sn1.v;
    if (mode == 1){
        *(float4*)&Hv32[gbase]     = hn0.v;
        *(float4*)&Hv32[gbase + 4] = hn1.v;
    }
    // Hnew in a-frag layout: rg=grow/16, kb=hgrp, lane=lqq*16+(grow&15)
    *(f16x8*)(Hnewf + (((size_t)(grow >> 4)*16 + hgrp)*64 + lqq*16 + (grow & 15))*8) = hh.v;
}

// ---------------------------------------------------------------------------
// Predict (32 rows per pblk), LDS-free B/A: frag weights + frag H.
// p0=leaky(H@W0+b0), p1=leaky(p0@W1+b1), val=sigmoid(dot(p1,Wf)+bf) (*gmul).
// lds: [0,16384) p0 a-frag halves; sums at +16384 ([4][32] fp32).
// ---------------------------------------------------------------------------
__device__ __forceinline__ void predict_dev(
    int pblk, const unsigned short* __restrict__ Hf,
    const unsigned short* __restrict__ W0f, const float* __restrict__ b0,
    const unsigned short* __restrict__ W1f, const float* __restrict__ b1,
    const float* __restrict__ Wf, const float* __restrict__ bf_,
    float* gstate, const float* __restrict__ gmul, float* pred, char* lds)
{
    char*  ldsP = lds;
    float* sums = (float*)(lds + 16384);
    const int tid = threadIdx.x, lane = tid & 63, w = tid >> 6;
    const int lr = lane & 15, lq = lane >> 4;

    f32x4 acc0[2][4];
#pragma unroll
    for (int m = 0; m < 2; ++m)
#pragma unroll
        for (int n = 0; n < 4; ++n){ f32x4 z = {0.f,0.f,0.f,0.f}; acc0[m][n] = z; }

    for (int kb = 0; kb < 16; ++kb){
        f16x8 a[2];
#pragma unroll
        for (int m = 0; m < 2; ++m) a[m] = AFRAG(Hf, pblk*2 + m, 16, kb);
#pragma unroll
        for (int n = 0; n < 4; ++n){
            f16x8 b = BFRAG(W0f, w*4 + n, 16, kb);
#pragma unroll
            for (int m = 0; m < 2; ++m)
                acc0[m][n] = __builtin_amdgcn_mfma_f32_16x16x32_f16(a[m], b, acc0[m][n], 0,0,0);
        }
    }
    // p0 epilogue -> LDS in a-frag layout (rg2=m, kb2=col/32, lane2, e2)
#pragma unroll
    for (int m = 0; m < 2; ++m){
#pragma unroll
        for (int n = 0; n < 4; ++n){
            const int col = w*64 + n*16 + lr;
            const float bs = b0[col];
            const int kb2 = col >> 5, lq2 = (col >> 3) & 3, e2 = col & 7;
#pragma unroll
            for (int r = 0; r < 4; ++r){
                const int row = m*16 + lq*4 + r;
                float x = acc0[m][n][r] + bs;
                x = (x > 0.0f) ? x : ALPHA*x;
                ((unsigned short*)ldsP)[((m*8 + kb2)*64 + lq2*16 + (row & 15))*8 + e2] = f2h(x);
            }
        }
    }
    __syncthreads();

    f32x4 accp[2][2];
#pragma unroll
    for (int m = 0; m < 2; ++m)
#pragma unroll
        for (int n = 0; n < 2; ++n){ f32x4 z = {0.f,0.f,0.f,0.f}; accp[m][n] = z; }

    for (int kb = 0; kb < 8; ++kb){
        f16x8 a[2];
#pragma unroll
        for (int m = 0; m < 2; ++m)
            a[m] = *(const f16x8*)((unsigned short*)ldsP + (((m*8 + kb)*64 + lane))*8);
#pragma unroll
        for (int n = 0; n < 2; ++n){
            f16x8 b = BFRAG(W1f, w*2 + n, 8, kb);
#pragma unroll
            for (int m = 0; m < 2; ++m)
                accp[m][n] = __builtin_amdgcn_mfma_f32_16x16x32_f16(a[m], b, accp[m][n], 0,0,0);
        }
    }

    float part[8];
#pragma unroll
    for (int j = 0; j < 8; ++j) part[j] = 0.0f;
#pragma unroll
    for (int m = 0; m < 2; ++m){
#pragma unroll
        for (int n = 0; n < 2; ++n){
            const int col = w*32 + n*16 + lr;
            const float bs = b1[col], wf = Wf[col];
#pragma unroll
            for (int r = 0; r < 4; ++r){
                float x = accp[m][n][r] + bs;
                x = (x > 0.0f) ? x : ALPHA*x;
                part[m*4 + r] += x * wf;
            }
        }
    }
#pragma unroll
    for (int mask = 1; mask < 16; mask <<= 1)
#pragma unroll
        for (int j = 0; j < 8; ++j) part[j] += __shfl_xor(part[j], mask);
    if (lr == 0){
#pragma unroll
        for (int j = 0; j < 8; ++j){
            const int row = (j >> 2)*16 + lq*4 + (j & 3);
            sums[w*32 + row] = part[j];
        }
    }
    __syncthreads();
    if (tid < 32){
        float tot = sums[tid] + sums[32 + tid] + sums[64 + tid] + sums[96 + tid] + bf_[0];
        float val = sigmoidf_(tot);
        const int rowg = pblk*32 + tid;
        if (gmul)   val *= gmul[rowg];
        if (gstate) gstate[rowg] = val;
        if (pred)   pred[rowg]   = val;
    }
}

// x -> a-frag fp16: 128 blocks x 256 thr x 2 chunks (65536 chunks total).
__device__ __forceinline__ void xf_dev(int blk, const float* __restrict__ x,
                                       unsigned short* __restrict__ Xf)
{
    const int t0 = blk*256 + threadIdx.x;
#pragma unroll
    for (int rep = 0; rep < 2; ++rep){
        const int gch = t0 + rep*32768;
        const int rg = gch >> 9, kb = (gch >> 6) & 7, ln = gch & 63;
        const int lrr = ln & 15, lqq = ln >> 4;
        const float* src = x + (size_t)(rg*16 + lrr)*E_DIM + kb*32 + lqq*8;
        float4 v0 = *(const float4*)src, v1 = *(const float4*)(src + 4);
        union { unsigned short u[8]; f16x8 v; } hh;
        hh.u[0]=f2h(v0.x); hh.u[1]=f2h(v0.y); hh.u[2]=f2h(v0.z); hh.u[3]=f2h(v0.w);
        hh.u[4]=f2h(v1.x); hh.u[5]=f2h(v1.y); hh.u[6]=f2h(v1.z); hh.u[7]=f2h(v1.w);
        *(f16x8*)(Xf + (size_t)gch*8) = hh.v;
    }
}

// ---------------------------------------------------------------------------
// LB: [0,64) predict_c (writes gnew,pred_c) | [64,128) predict_v(t-1) (gold)
//     | [128,256) x(t+1) -> frag
// ---------------------------------------------------------------------------
__global__ __launch_bounds__(256) void k_LB(
    const unsigned short* __restrict__ Hcnf,
    const unsigned short* __restrict__ W0fc, const float* __restrict__ bpc0,
    const unsigned short* __restrict__ W1fc, const float* __restrict__ bpc1,
    const float* __restrict__ Wfcc, const float* __restrict__ bfcc,
    float* __restrict__ gnew, float* __restrict__ predc,
    const unsigned short* __restrict__ Hvbf,
    const unsigned short* __restrict__ W0fv, const float* __restrict__ bpv0,
    const unsigned short* __restrict__ W1fv, const float* __restrict__ bpv1,
    const float* __restrict__ Wfcv, const float* __restrict__ bfcv,
    const float* __restrict__ gold, float* __restrict__ predv,
    const float* __restrict__ xnext, unsigned short* __restrict__ Xnf)
{
    __shared__ __align__(16) char lds[16896];
    const int id = blockIdx.x;
    if (id < 64){
        predict_dev(id, Hcnf, W0fc, bpc0, W1fc, bpc1, Wfcc, bfcc,
                    gnew, nullptr, predc, lds);
    } else if (id < 128){
        if (predv) predict_dev(id - 64, Hvbf, W0fv, bpv0, W1fv, bpv1, Wfcv, bfcv,
                               nullptr, gold, predv, lds);
    } else {
        if (Xnf) xf_dev(id - 128, xnext, Xnf);
    }
}

__global__ __launch_bounds__(256) void k_predict_g(
    const unsigned short* __restrict__ Hf,
    const unsigned short* __restrict__ W0f, const float* __restrict__ b0,
    const unsigned short* __restrict__ W1f, const float* __restrict__ b1,
    const float* __restrict__ Wf, const float* __restrict__ bf_,
    float* gstate, const float* __restrict__ gmul, float* pred)
{
    __shared__ __align__(16) char lds[16896];
    predict_dev(blockIdx.x, Hf, W0f, b0, W1f, b1, Wf, bf_, gstate, gmul, pred, lds);
}

__global__ __launch_bounds__(256) void k_xf_g(const float* __restrict__ x,
                                              unsigned short* __restrict__ Xf)
{
    xf_dev(blockIdx.x, x, Xf);
}

// ---------------------------------------------------------------------------
// One-time weight -> b-frag prep kernels.
// ---------------------------------------------------------------------------
// Wgf[cg 128][kbg 24][64][8]: col' cg: hgrp=cg/8, n16=cg%8; col128=n16*16+lr;
// z=col128/32, hl=col128%32, h=hgrp*32+hl; k=kbg*32+lq*8+e (X k<256 else H).
__global__ __launch_bounds__(256) void k_wgf(const float* __restrict__ Wx,
                                             const float* __restrict__ Wh,
                                             unsigned short* __restrict__ out){
    const int kbg = blockIdx.x, cg = blockIdx.y;
    const int t = threadIdx.x;
    const int ln = t >> 2, eq = (t & 3) * 2;
    const int lrr = ln & 15, lqq = ln >> 4;
    const int hgrp = cg >> 3, n16 = cg & 7;
    const int col128 = n16*16 + lrr;
    const int z = col128 >> 5, hl = col128 & 31;
    const int h = hgrp*32 + hl;
    const size_t off = (((size_t)cg*24 + kbg)*64 + ln)*8 + eq;
#pragma unroll
    for (int e = 0; e < 2; ++e){
        const int k = kbg*32 + lqq*8 + eq + e;
        const float v = (k < 256) ? Wx[((size_t)z*E_DIM + k)*H_DIM + h]
                                  : Wh[((size_t)z*H_DIM + (k - 256))*H_DIM + h];
        out[off + e] = f2h(v);
    }
}

// Wsf[i][cg 32][kb 16][64][8] from Ws[i][k][col].
__global__ __launch_bounds__(256) void k_wsf(const float* __restrict__ Ws,
                                             unsigned short* __restrict__ out){
    const int kb = blockIdx.x, icg = blockIdx.y;
    const int i = icg >> 5, cg = icg & 31;
    const int t = threadIdx.x;
    const int ln = t >> 2, eq = (t & 3) * 2;
    const int lrr = ln & 15, lqq = ln >> 4;
    const int col = cg*16 + lrr;
    const size_t off = ((((size_t)i*32 + cg)*16 + kb)*64 + ln)*8 + eq;
#pragma unroll
    for (int e = 0; e < 2; ++e){
        const int k = kb*32 + lqq*8 + eq + e;
        out[off + e] = f2h(Ws[((size_t)i*H_DIM + k)*H_DIM + col]);
    }
}

// Generic [K][N] -> b-frag [N/16][K/32][64][8].
__global__ __launch_bounds__(256) void k_wpf(const float* __restrict__ W,
                                             unsigned short* __restrict__ out,
                                             int K, int N){
    const int kb = blockIdx.x, cg = blockIdx.y;
    const int t = threadIdx.x;
    const int ln = t >> 2, eq = (t & 3) * 2;
    const int lrr = ln & 15, lqq = ln >> 4;
    const int col = cg*16 + lrr;
    const int NKB = K >> 5;
    const size_t off = (((size_t)cg*NKB + kb)*64 + ln)*8 + eq;
#pragma unroll
    for (int e = 0; e < 2; ++e){
        const int k = kb*32 + lqq*8 + eq + e;
        out[off + e] = f2h(W[(size_t)k*N + col]);
    }
}

__global__ __launch_bounds__(256) void k_init(float* __restrict__ sc, float* __restrict__ sv,
                                              float* __restrict__ hv32,
                                              unsigned short* __restrict__ hc0,
                                              unsigned short* __restrict__ hv0){
    const int i = blockIdx.x*256 + threadIdx.x;
    sc[i] = 0.0f; sv[i] = 0.0f; hv32[i] = 0.0f;
    hc0[i] = 0; hv0[i] = 0;
}

// ---------------------------------------------------------------------------
extern "C" void kernel_launch(void* const* d_in, const int* in_sizes, int n_in,
                              void* d_out, int out_size, void* d_ws, size_t ws_size,
                              hipStream_t stream)
{
    (void)in_sizes; (void)n_in; (void)out_size; (void)ws_size;

    const float* inputs = (const float*)d_in[0];
    const float* Wx_c   = (const float*)d_in[1];
    const float* bx_c   = (const float*)d_in[2];
    const float* Wh_c   = (const float*)d_in[3];
    const float* Wx_v   = (const float*)d_in[4];
    const float* bx_v   = (const float*)d_in[5];
    const float* Wh_v   = (const float*)d_in[6];
    const float* Ws     = (const float*)d_in[7];
    const float* Wpc0   = (const float*)d_in[8];
    const float* bpc0   = (const float*)d_in[9];
    const float* Wpc1   = (const float*)d_in[10];
    const float* bpc1   = (const float*)d_in[11];
    const float* Wfcc   = (const float*)d_in[12];
    const float* bfcc   = (const float*)d_in[13];
    const float* Wpv0   = (const float*)d_in[14];
    const float* bpv0   = (const float*)d_in[15];
    const float* Wpv1   = (const float*)d_in[16];
    const float* bpv1   = (const float*)d_in[17];
    const float* Wfcv   = (const float*)d_in[18];
    const float* bfcv   = (const float*)d_in[19];
    float* out = (float*)d_out;

    char* ws = (char*)d_ws;
    size_t off = 0;
    auto allocB = [&](size_t bytes) -> char* {
        char* p = ws + off;
        off = (off + bytes + 255) & ~(size_t)255;
        return p;
    };
    const size_t BH = (size_t)BATCH * H_DIM;
    const size_t BE = (size_t)BATCH * E_DIM;

    unsigned short* Xf[2];
    Xf[0] = (unsigned short*)allocB(BE*2);
    Xf[1] = (unsigned short*)allocB(BE*2);
    unsigned short* Wgfc = (unsigned short*)allocB((size_t)128*24*64*8*2);
    unsigned short* Wgfv = (unsigned short*)allocB((size_t)128*24*64*8*2);
    unsigned short* Wsf  = (unsigned short*)allocB((size_t)4*32*16*64*8*2);
    unsigned short* W0fc = (unsigned short*)allocB((size_t)16*16*64*8*2);
    unsigned short* W0fv = (unsigned short*)allocB((size_t)16*16*64*8*2);
    unsigned short* W1fc = (unsigned short*)allocB((size_t)8*8*64*8*2);
    unsigned short* W1fv = (unsigned short*)allocB((size_t)8*8*64*8*2);
    unsigned short* Hcf[2], *Hvf[2];
    Hcf[0] = (unsigned short*)allocB(BH*2);
    Hcf[1] = (unsigned short*)allocB(BH*2);
    Hvf[0] = (unsigned short*)allocB(BH*2);
    Hvf[1] = (unsigned short*)allocB(BH*2);
    float* sc    = (float*)allocB(BH*4);
    float* sv    = (float*)allocB(BH*4);
    float* hv32  = (float*)allocB(BH*4);
    float* gbuf[2];
    gbuf[0] = (float*)allocB(BATCH*4);
    gbuf[1] = (float*)allocB(BATCH*4);

    const dim3 thr(256);
    const size_t WSFM = (size_t)32*16*64*8;   // halves per Ws frag matrix

    // ---- one-time weight conversion to frag layouts ----
    k_wgf<<<dim3(24, 128), thr, 0, stream>>>(Wx_c, Wh_c, Wgfc);
    k_wgf<<<dim3(24, 128), thr, 0, stream>>>(Wx_v, Wh_v, Wgfv);
    k_wsf<<<dim3(16, 128), thr, 0, stream>>>(Ws, Wsf);
    k_wpf<<<dim3(16, 16), thr, 0, stream>>>(Wpc0, W0fc, H_DIM, P0_DIM);
    k_wpf<<<dim3(16, 16), thr, 0, stream>>>(Wpv0, W0fv, H_DIM, P0_DIM);
    k_wpf<<<dim3(8, 8),   thr, 0, stream>>>(Wpc1, W1fc, P0_DIM, P1_DIM);
    k_wpf<<<dim3(8, 8),   thr, 0, stream>>>(Wpv1, W1fv, P0_DIM, P1_DIM);

    // ---- init: zero states; g0 = predict_c(zeros) -> gbuf[0]; x(0) -> frag ----
    k_init<<<4096, thr, 0, stream>>>(sc, sv, hv32, Hcf[0], Hvf[0]);
    k_predict_g<<<64, thr, 0, stream>>>(Hcf[0], W0fc, bpc0, W1fc, bpc1, Wfcc, bfcc,
                                        gbuf[0], nullptr, nullptr);
    k_xf_g<<<128, thr, 0, stream>>>(inputs, Xf[0]);

    for (int t = 0; t < T_STEPS; ++t){
        const int cur = t & 1, nxt = cur ^ 1;

        // LA: fused click stream (gates_c + a1 + a2 + cell_c)
        k_fused<<<512, thr, 0, stream>>>(Xf[cur], Hcf[cur], Hvf[cur],
                                         Wgfc, bx_c,
                                         Wsf + 0*WSFM,   // Ws0 -> extraH = a1
                                         Wsf + 1*WSFM,   // Ws1 -> extraV = a2
                                         gbuf[cur], sc, nullptr, Hcf[nxt], 0);

        // LB: predict_c (g_new) + predict_v(t-1) (g_old) + x(t+1) frag
        k_LB<<<256, thr, 0, stream>>>(Hcf[nxt], W0fc, bpc0, W1fc, bpc1, Wfcc, bfcc,
                                      gbuf[nxt], out + (size_t)t*BATCH,
                                      Hvf[cur], W0fv, bpv0, W1fv, bpv1, Wfcv, bfcv,
                                      gbuf[cur],
                                      (t > 0) ? out + (size_t)(T_STEPS + t - 1)*BATCH
                                              : nullptr,
                                      inputs + (size_t)(t+1)*BE,
                                      (t + 1 < T_STEPS) ? Xf[nxt] : nullptr);

        // LC: fused conversion stream (gates_v + a2v + a1v + cell_v)
        k_fused<<<512, thr, 0, stream>>>(Xf[cur], Hcf[nxt], Hvf[cur],
                                         Wgfv, bx_v,
                                         Wsf + 3*WSFM,   // Ws3 -> extraH = a2v
                                         Wsf + 2*WSFM,   // Ws2 -> extraV = a1v
                                         gbuf[nxt], sv, hv32, Hvf[nxt], 1);
    }
    // tail: pred_v(T-1); Hvf_new(199)=Hvf[0], g_new(199)=gbuf[0]
    k_predict_g<<<64, thr, 0, stream>>>(Hvf[0], W0fv, bpv0, W1fv, bpv1, Wfcv, bfcv,
                                        nullptr, gbuf[0],
                                        out + (size_t)(2*T_STEPS - 1)*BATCH);
}

// Round 13
// 14719.577 us; speedup vs baseline: 1.0799x; 1.0799x over previous
//
#include <hip/hip_runtime.h>
#include <cstdint>
#include <cstddef>

constexpr int T_STEPS = 200;
constexpr int BATCH   = 2048;
constexpr int E_DIM   = 256;
constexpr int H_DIM   = 512;
constexpr int P0_DIM  = 256;
constexpr int P1_DIM  = 128;
constexpr float ALPHA = 0.3f;

typedef __attribute__((ext_vector_type(8))) _Float16 f16x8;
typedef __attribute__((ext_vector_type(4))) float f32x4;

__device__ __forceinline__ float sigmoidf_(float x){ return 1.0f/(1.0f+expf(-x)); }

__device__ __forceinline__ unsigned short f2h(float f){
    union { _Float16 h; unsigned short u; } v;
    v.h = (_Float16)f;                 // v_cvt_f16_f32, RNE
    return v.u;
}

#define GLOAD16(gp, lp) __builtin_amdgcn_global_load_lds( \
    (const __attribute__((address_space(1))) unsigned int*)(gp), \
    (__attribute__((address_space(3))) unsigned int*)(lp), 16, 0, 0)

// Stage a [ROWS][64] 16-bit tile into linear LDS, slot-swizzled at the SOURCE
// (m173 pattern): LDS[r][s] holds global k-slot (s ^ (r&7)) of row r.
template<int ROWS>
__device__ __forceinline__ void stage64(const unsigned short* __restrict__ src, int ldk,
                                        char* ldsbase){
    constexpr int TOT = ROWS * 8;          // 16B slots
    const int tid = threadIdx.x;
#pragma unroll
    for (int i = 0; i < TOT/256; ++i){
        const int gsl = i*256 + tid;
        const int r = gsl >> 3, s = gsl & 7;
        const int ksrc = ((s ^ (r & 7)) << 3);
        GLOAD16(src + (size_t)r*ldk + ksrc, ldsbase + gsl*16);
    }
}

// Swizzled b128 fragment read: row-stride 128B (BK=64), kslot in [0,8).
__device__ __forceinline__ f16x8 ldsfragh(const char* ldsbase, int row, int kslot){
    return *(const f16x8*)(ldsbase + row*128 + ((kslot ^ (row & 7)) << 4));
}

// ---------------------------------------------------------------------------
// Fused-phase K loop, 128-row A tiles (double-buffered, counted vmcnt).
// Per-buf layout: A[128] at +0 (16KB), B1[128] at +16384 (16KB),
// B2[32] at +32768 (4KB); bufs at 0 / 36864. 72KB total.
// accg: gates acc, wave rows wr*64+[0,64), cols wc*64+[0,64) (4x4 frags).
// acce: extra acc, wave rows wr*64+[0,64), cols wc*16+[0,16) (4x1 frags).
// ---------------------------------------------------------------------------
template<bool HAS_B1, bool HAS_B2, int KSLABS>
__device__ __forceinline__ void fused_phase(
    const unsigned short* __restrict__ A, int lda,
    const unsigned short* __restrict__ B1,
    const unsigned short* __restrict__ B2,
    f32x4 (&accg)[4][4], f32x4 (&acce)[4],
    char* lds, int wr, int wc, int lr, int lq)
{
    stage64<128>(A, lda, lds);
    if (HAS_B1) stage64<128>(B1, 768, lds + 16384);
    if (HAS_B2) stage64<32>(B2, 512, lds + 32768);
    int cur = 0;
    for (int s = 0; s < KSLABS; ++s){
        char* bufc = lds + cur*36864;
        if (s + 1 < KSLABS){
            char* bufn = lds + (cur^1)*36864;
            stage64<128>(A + (s+1)*64, lda, bufn);
            if (HAS_B1) stage64<128>(B1 + (s+1)*64, 768, bufn + 16384);
            if (HAS_B2) stage64<32>(B2 + (s+1)*64, 512, bufn + 32768);
            if constexpr (HAS_B1 && HAS_B2)
                asm volatile("s_waitcnt vmcnt(9)" ::: "memory");
            else if constexpr (HAS_B1)
                asm volatile("s_waitcnt vmcnt(8)" ::: "memory");
            else
                asm volatile("s_waitcnt vmcnt(5)" ::: "memory");
        } else {
            asm volatile("s_waitcnt vmcnt(0)" ::: "memory");
        }
        __builtin_amdgcn_s_barrier();
        __builtin_amdgcn_sched_barrier(0);
        __builtin_amdgcn_s_setprio(1);
#pragma unroll
        for (int kk = 0; kk < 2; ++kk){
            f16x8 a[4];
#pragma unroll
            for (int m = 0; m < 4; ++m) a[m] = ldsfragh(bufc, wr*64 + m*16 + lr, kk*4 + lq);
            if (HAS_B1){
#pragma unroll
                for (int n = 0; n < 4; ++n){
                    f16x8 b = ldsfragh(bufc + 16384, wc*64 + n*16 + lr, kk*4 + lq);
#pragma unroll
                    for (int m = 0; m < 4; ++m)
                        accg[m][n] = __builtin_amdgcn_mfma_f32_16x16x32_f16(a[m], b, accg[m][n], 0,0,0);
                }
            }
            if (HAS_B2){
                f16x8 bx = ldsfragh(bufc + 32768, wc*16 + lr, kk*4 + lq);
#pragma unroll
                for (int m = 0; m < 4; ++m)
                    acce[m] = __builtin_amdgcn_mfma_f32_16x16x32_f16(a[m], bx, acce[m], 0,0,0);
            }
        }
        __builtin_amdgcn_s_setprio(0);
        __builtin_amdgcn_sched_barrier(0);
        __builtin_amdgcn_s_barrier();
        cur ^= 1;
    }
}

// ---------------------------------------------------------------------------
// Fused stream kernel: 256 blocks = 16 brow-groups (128 rows) x 16 h-groups.
//   gates(128x128, K=768: X then AH) + extraH(128x32 = AH@WsH, K=512)
//   + extraV(128x32 = AV@WsV, K=512) + inline cell update (two 64-row halves).
// mode 0 (click): a1=extraH(Hc@Ws0), a2=extraV(Hv@Ws1); writes sc, Hc_new.
// mode 1 (conv):  a1=extraV(Hv@Ws2), a2=extraH(Hc@Ws3); writes sv, hv32, Hv_new.
// WT2 layout: [2048][768], n' = (h/32)*128 + z*32 + (h%32).
// ---------------------------------------------------------------------------
__global__ __launch_bounds__(256, 1) void k_fused(
    const unsigned short* __restrict__ Xh,
    const unsigned short* __restrict__ AH,   // Hc_old (mode 0) / Hc_new (mode 1)
    const unsigned short* __restrict__ AV,   // Hv_old
    const unsigned short* __restrict__ WT2,
    const float* __restrict__ bias,          // [4][512] z-major
    const unsigned short* __restrict__ WsH,  // Ws0 (mode 0) / Ws3 (mode 1)
    const unsigned short* __restrict__ WsV,  // Ws1 (mode 0) / Ws2 (mode 1)
    const float* __restrict__ g,
    float* __restrict__ sstate, float* __restrict__ Hv32,
    unsigned short* __restrict__ Hnew,
    const int mode)
{
    __shared__ __align__(16) char lds[73728];
    const int tid = threadIdx.x;
    const int lane = tid & 63, wid = tid >> 6;
    const int wr = wid >> 1, wc = wid & 1;
    const int lr = lane & 15, lq = lane >> 4;

    // XCD-bijective swizzle: XCD k gets virt [k*32,(k+1)*32) = hgrps {2k,2k+1}.
    const int id = blockIdx.x;
    const int virt = ((id & 7) << 5) | (id >> 3);
    const int hgrp = virt >> 4;      // 0..15
    const int brow = (virt & 15) * 128;
    const int h0   = hgrp * 32;

    f32x4 accg[4][4], acceH[4], acceV[4];
#pragma unroll
    for (int m = 0; m < 4; ++m){
        f32x4 z = {0.f,0.f,0.f,0.f};
#pragma unroll
        for (int n = 0; n < 4; ++n) accg[m][n] = z;
        acceH[m] = z; acceV[m] = z;
    }

    const unsigned short* WTp = WT2 + (size_t)hgrp*128*768;
    // phase X: gates k 0..255
    fused_phase<true,false,4>(Xh + (size_t)brow*E_DIM, E_DIM, WTp, nullptr,
                              accg, acceH, lds, wr, wc, lr, lq);
    // phase H: gates k 256..767 + extraH k 0..511 (shared A staging)
    fused_phase<true,true,8>(AH + (size_t)brow*H_DIM, H_DIM, WTp + E_DIM,
                             WsH + (size_t)h0*H_DIM,
                             accg, acceH, lds, wr, wc, lr, lq);
    // phase V: extraV k 0..511
    fused_phase<false,true,8>(AV + (size_t)brow*H_DIM, H_DIM, nullptr,
                              WsV + (size_t)h0*H_DIM,
                              accg, acceV, lds, wr, wc, lr, lq);

    // ---- epilogue in two 64-row halves (waves wr==ph own half ph) ----
    float* ldsG  = (float*)lds;               // [64][132] fp32
    float* ldsEH = (float*)(lds + 33792);     // [64][33]
    float* ldsEV = (float*)(lds + 42240);     // [64][33]
    for (int ph = 0; ph < 2; ++ph){
        __syncthreads();
        if (wr == ph){
#pragma unroll
            for (int m = 0; m < 4; ++m){
#pragma unroll
                for (int n = 0; n < 4; ++n){
                    const int col = wc*64 + n*16 + lr;      // z*32 + hl
                    const int z = col >> 5, hl = col & 31;
                    const float bs = bias[z*H_DIM + h0 + hl];
#pragma unroll
                    for (int r = 0; r < 4; ++r){
                        const int rowl = m*16 + lq*4 + r;   // 0..63 local
                        float v = accg[m][n][r] + bs;
                        v = (z < 3) ? sigmoidf_(v) : tanhf(v);
                        ldsG[rowl*132 + col] = v;
                    }
                }
                const int col2 = wc*16 + lr;
#pragma unroll
                for (int r = 0; r < 4; ++r){
                    const int rowl = m*16 + lq*4 + r;
                    ldsEH[rowl*33 + col2] = acceH[m][r];
                    ldsEV[rowl*33 + col2] = acceV[m][r];
                }
            }
        }
        __syncthreads();

        // ---- inline cell: 256 threads x 8 elems (r10-verified math) ----
        const int crow = tid >> 2, lqq = tid & 3, ch = lqq * 8;
        const int grow = brow + ph*64 + crow;
        const float gv = g[grow];
        const size_t gbase = (size_t)grow*H_DIM + h0 + ch;
        union U4 { float4 v; float s[4]; };
        U4 sv0, sv1, hv0, hv1;
        sv0.v = *(const float4*)&sstate[gbase];
        sv1.v = *(const float4*)&sstate[gbase + 4];
        if (mode == 1){
            hv0.v = *(const float4*)&Hv32[gbase];
            hv1.v = *(const float4*)&Hv32[gbase + 4];
        }
        U4 sn0, sn1, hn0, hn1;
        union { unsigned short u[8]; f16x8 v; } hu;
#pragma unroll
        for (int e = 0; e < 8; ++e){
            const int hc = ch + e;
            const float f_ = ldsG[crow*132 + hc];
            const float i_ = ldsG[crow*132 + 32 + hc];
            const float o_ = ldsG[crow*132 + 64 + hc];
            const float q_ = ldsG[crow*132 + 96 + hc];
            const float eh = ldsEH[crow*33 + hc];
            const float ev = ldsEV[crow*33 + hc];
            const float a1 = (mode == 0) ? eh : ev;
            const float a2 = (mode == 0) ? ev : eh;
            const float svo = (e < 4) ? sv0.s[e] : sv1.s[e-4];
            float s, hval;
            if (mode == 0){
                const float shat = tanhf((1.0f - gv)*a1 + gv*a2);
                s = shat + i_*q_ + (1.0f - gv)*(f_*svo);
                hval = o_ * tanhf(s);
            } else {
                const float shat = tanhf(a1 + gv*a2);
                s = shat + (1.0f - gv)*svo + gv*(f_*svo + i_*q_);
                const float hvo = (e < 4) ? hv0.s[e] : hv1.s[e-4];
                hval = (1.0f - gv)*hvo + gv*(o_*tanhf(s));
                if (e < 4) hn0.s[e] = hval; else hn1.s[e-4] = hval;
            }
            if (e < 4) sn0.s[e] = s; else sn1.s[e-4] = s;
            hu.u[e] = f2h(hval);
        }
        *(float4*)&sstate[gbase]     = sn0.v;
        *(float4*)&sstate[gbase + 4] = sn1.v;
        if (mode == 1){
            *(float4*)&Hv32[gbase]     = hn0.v;
            *(float4*)&Hv32[gbase + 4] = hn1.v;
        }
        *(f16x8*)&Hnew[gbase] = hu.v;
    }
}

// ---------------------------------------------------------------------------
// Predict (32 rows per pblk): p0=leaky(H@W0+b0), p1=leaky(p0@W1+b1),
// val=sigmoid(dot(p1,Wf)+bf) (*gmul). r10-verified (LDS-staged).
// ---------------------------------------------------------------------------
__device__ __forceinline__ void predict_dev(
    int pblk, const unsigned short* __restrict__ Hh,
    const unsigned short* __restrict__ W0T, const float* __restrict__ b0,
    const unsigned short* __restrict__ W1T, const float* __restrict__ b1,
    const float* __restrict__ Wf, const float* __restrict__ bf_,
    float* gstate, const float* __restrict__ gmul, float* pred, char* lds)
{
    char*  ldsA = lds;                    // [32][128B]
    char*  ldsB = lds + 4096;             // up to [256][128B]
    char*  ldsP = lds + 36864;            // [32][512B] p0 fp16 (swizzled)
    float* sums = (float*)(lds + 53248);  // [4][32]
    const int tid = threadIdx.x, lane = tid & 63, w = tid >> 6;
    const int lr = lane & 15, lq = lane >> 4;
    const int brow = pblk * 32;

    f32x4 acc0[2][4];
#pragma unroll
    for (int m = 0; m < 2; ++m)
#pragma unroll
        for (int n = 0; n < 4; ++n){ f32x4 z = {0.f,0.f,0.f,0.f}; acc0[m][n] = z; }

    for (int k0 = 0; k0 < H_DIM; k0 += 64){
        stage64<32>(Hh + (size_t)brow*H_DIM + k0, H_DIM, ldsA);
        stage64<256>(W0T + k0, H_DIM, ldsB);
        __syncthreads();
#pragma unroll
        for (int kk = 0; kk < 2; ++kk){
            f16x8 a[2], b[4];
#pragma unroll
            for (int m = 0; m < 2; ++m) a[m] = ldsfragh(ldsA, m*16 + lr, kk*4 + lq);
#pragma unroll
            for (int n = 0; n < 4; ++n) b[n] = ldsfragh(ldsB, w*64 + n*16 + lr, kk*4 + lq);
#pragma unroll
            for (int m = 0; m < 2; ++m)
#pragma unroll
                for (int n = 0; n < 4; ++n)
                    acc0[m][n] = __builtin_amdgcn_mfma_f32_16x16x32_f16(a[m], b[n], acc0[m][n], 0,0,0);
        }
        __syncthreads();
    }
#pragma unroll
    for (int m = 0; m < 2; ++m){
#pragma unroll
        for (int n = 0; n < 4; ++n){
            const int col = w*64 + n*16 + lr;
            const float bs = b0[col];
#pragma unroll
            for (int r = 0; r < 4; ++r){
                const int row = m*16 + lq*4 + r;
                float x = acc0[m][n][r] + bs;
                x = (x > 0.0f) ? x : ALPHA*x;
                *(unsigned short*)(ldsP + row*512 + ((((col >> 3)) ^ (row & 7)) << 4) + (col & 7)*2) = f2h(x);
            }
        }
    }
    __syncthreads();

    f32x4 accp[2][2];
#pragma unroll
    for (int m = 0; m < 2; ++m)
#pragma unroll
        for (int n = 0; n < 2; ++n){ f32x4 z = {0.f,0.f,0.f,0.f}; accp[m][n] = z; }

    for (int k0 = 0; k0 < P0_DIM; k0 += 64){
        stage64<128>(W1T + k0, P0_DIM, ldsB);
        __syncthreads();
#pragma unroll
        for (int kk = 0; kk < 2; ++kk){
            f16x8 a[2], b[2];
#pragma unroll
            for (int m = 0; m < 2; ++m){
                const int row = m*16 + lr;
                const int slot = (k0 >> 3) + kk*4 + lq;
                a[m] = *(const f16x8*)(ldsP + row*512 + ((slot ^ (row & 7)) << 4));
            }
#pragma unroll
            for (int n = 0; n < 2; ++n) b[n] = ldsfragh(ldsB, w*32 + n*16 + lr, kk*4 + lq);
#pragma unroll
            for (int m = 0; m < 2; ++m)
#pragma unroll
                for (int n = 0; n < 2; ++n)
                    accp[m][n] = __builtin_amdgcn_mfma_f32_16x16x32_f16(a[m], b[n], accp[m][n], 0,0,0);
        }
        __syncthreads();
    }

    float part[8];
#pragma unroll
    for (int j = 0; j < 8; ++j) part[j] = 0.0f;
#pragma unroll
    for (int m = 0; m < 2; ++m){
#pragma unroll
        for (int n = 0; n < 2; ++n){
            const int col = w*32 + n*16 + lr;
            const float bs = b1[col], wf = Wf[col];
#pragma unroll
            for (int r = 0; r < 4; ++r){
                float x = accp[m][n][r] + bs;
                x = (x > 0.0f) ? x : ALPHA*x;
                part[m*4 + r] += x * wf;
            }
        }
    }
#pragma unroll
    for (int mask = 1; mask < 16; mask <<= 1)
#pragma unroll
        for (int j = 0; j < 8; ++j) part[j] += __shfl_xor(part[j], mask);
    if (lr == 0){
#pragma unroll
        for (int j = 0; j < 8; ++j){
            const int row = (j >> 2)*16 + lq*4 + (j & 3);
            sums[w*32 + row] = part[j];
        }
    }
    __syncthreads();
    if (tid < 32){
        float tot = sums[tid] + sums[32 + tid] + sums[64 + tid] + sums[96 + tid] + bf_[0];
        float val = sigmoidf_(tot);
        const int rowg = brow + tid;
        if (gmul)   val *= gmul[rowg];
        if (gstate) gstate[rowg] = val;
        if (pred)   pred[rowg]   = val;
    }
}

// x-step fp16 convert: 128 blocks x 256 thr x 4 float4.
__device__ __forceinline__ void xcvt_dev(int blk, const float* __restrict__ x,
                                         unsigned short* __restrict__ oh)
{
    const int tid = threadIdx.x;
#pragma unroll
    for (int j = 0; j < 4; ++j){
        const int t = blk*256 + tid + j*32768;
        float4 v = ((const float4*)x)[t];
        ushort4 h;
        h.x = f2h(v.x); h.y = f2h(v.y); h.z = f2h(v.z); h.w = f2h(v.w);
        ((ushort4*)oh)[t] = h;
    }
}

// ---------------------------------------------------------------------------
// LB: [0,64) predict_c (writes gnew, pred_c) | [64,128) predict_v(t-1) reads gold
//     | [128,256) xcvt(t+1)
// ---------------------------------------------------------------------------
__global__ __launch_bounds__(256) void k_LB(
    const unsigned short* __restrict__ Hcn,
    const unsigned short* __restrict__ Wp0Tc, const float* __restrict__ bpc0,
    const unsigned short* __restrict__ Wp1Tc, const float* __restrict__ bpc1,
    const float* __restrict__ Wfcc, const float* __restrict__ bfcc,
    float* __restrict__ gnew, float* __restrict__ predc,
    const unsigned short* __restrict__ Hvb,
    const unsigned short* __restrict__ Wp0Tv, const float* __restrict__ bpv0,
    const unsigned short* __restrict__ Wp1Tv, const float* __restrict__ bpv1,
    const float* __restrict__ Wfcv, const float* __restrict__ bfcv,
    const float* __restrict__ gold, float* __restrict__ predv,
    const float* __restrict__ xnext, unsigned short* __restrict__ Xnh)
{
    __shared__ __align__(16) char lds[53760];
    const int id = blockIdx.x;
    if (id < 64){
        predict_dev(id, Hcn, Wp0Tc, bpc0, Wp1Tc, bpc1, Wfcc, bfcc,
                    gnew, nullptr, predc, lds);
    } else if (id < 128){
        if (predv) predict_dev(id - 64, Hvb, Wp0Tv, bpv0, Wp1Tv, bpv1, Wfcv, bfcv,
                               nullptr, gold, predv, lds);
    } else {
        if (Xnh) xcvt_dev(id - 128, xnext, Xnh);
    }
}

// ---------------------------------------------------------------------------
// Standalone predict (init g0 / final pred_v) and x0 convert.
// ---------------------------------------------------------------------------
__global__ __launch_bounds__(256) void k_predict_g(
    const unsigned short* __restrict__ Hh,
    const unsigned short* __restrict__ W0T, const float* __restrict__ b0,
    const unsigned short* __restrict__ W1T, const float* __restrict__ b1,
    const float* __restrict__ Wf, const float* __restrict__ bf_,
    float* gstate, const float* __restrict__ gmul, float* pred)
{
    __shared__ __align__(16) char lds[53760];
    predict_dev(blockIdx.x, Hh, W0T, b0, W1T, b1, Wf, bf_, gstate, gmul, pred, lds);
}

__global__ __launch_bounds__(256) void k_xcvt_g(const float* __restrict__ x,
                                                unsigned short* __restrict__ oh)
{
    xcvt_dev(blockIdx.x, x, oh);
}

// ---------------------------------------------------------------------------
// Prep kernels. WT2 layout: n' = (h/32)*128 + z*32 + (h%32), k in [0,768).
// ---------------------------------------------------------------------------
__global__ __launch_bounds__(256) void k_wcat(const float* __restrict__ Wx,
                                              const float* __restrict__ Wh,
                                              unsigned short* __restrict__ oh){
    const int n = blockIdx.y;                 // n' in [0,2048)
    const int k = blockIdx.x*256 + threadIdx.x;
    const int z = (n >> 5) & 3;
    const int h = ((n >> 7) << 5) | (n & 31);
    float v = (k < 256) ? Wx[((size_t)z*E_DIM + k)*H_DIM + h]
                        : Wh[((size_t)z*H_DIM + (k - 256))*H_DIM + h];
    oh[(size_t)n*768 + k] = f2h(v);
}

__global__ __launch_bounds__(256) void k_trans(const float* __restrict__ in,
                                               unsigned short* __restrict__ oh,
                                               int K, int N){
    const int k = blockIdx.x*256 + threadIdx.x;
    const int n = blockIdx.y;
    if (k < K) oh[(size_t)n*K + k] = f2h(in[(size_t)k*N + n]);
}

__global__ __launch_bounds__(256) void k_init(float* __restrict__ sc, float* __restrict__ sv,
                                              float* __restrict__ hv32,
                                              unsigned short* __restrict__ hc0,
                                              unsigned short* __restrict__ hv0){
    const int i = blockIdx.x*256 + threadIdx.x;
    sc[i] = 0.0f; sv[i] = 0.0f; hv32[i] = 0.0f;
    hc0[i] = 0; hv0[i] = 0;
}

// ---------------------------------------------------------------------------
extern "C" void kernel_launch(void* const* d_in, const int* in_sizes, int n_in,
                              void* d_out, int out_size, void* d_ws, size_t ws_size,
                              hipStream_t stream)
{
    (void)in_sizes; (void)n_in; (void)out_size; (void)ws_size;

    const float* inputs = (const float*)d_in[0];
    const float* Wx_c   = (const float*)d_in[1];
    const float* bx_c   = (const float*)d_in[2];
    const float* Wh_c   = (const float*)d_in[3];
    const float* Wx_v   = (const float*)d_in[4];
    const float* bx_v   = (const float*)d_in[5];
    const float* Wh_v   = (const float*)d_in[6];
    const float* Ws     = (const float*)d_in[7];
    const float* Wpc0   = (const float*)d_in[8];
    const float* bpc0   = (const float*)d_in[9];
    const float* Wpc1   = (const float*)d_in[10];
    const float* bpc1   = (const float*)d_in[11];
    const float* Wfcc   = (const float*)d_in[12];
    const float* bfcc   = (const float*)d_in[13];
    const float* Wpv0   = (const float*)d_in[14];
    const float* bpv0   = (const float*)d_in[15];
    const float* Wpv1   = (const float*)d_in[16];
    const float* bpv1   = (const float*)d_in[17];
    const float* Wfcv   = (const float*)d_in[18];
    const float* bfcv   = (const float*)d_in[19];
    float* out = (float*)d_out;

    char* ws = (char*)d_ws;
    size_t off = 0;
    auto allocB = [&](size_t bytes) -> char* {
        char* p = ws + off;
        off = (off + bytes + 255) & ~(size_t)255;
        return p;
    };
    const size_t BH = (size_t)BATCH * H_DIM;
    const size_t BE = (size_t)BATCH * E_DIM;

    unsigned short* Xh[2];
    Xh[0] = (unsigned short*)allocB(BE*2);
    Xh[1] = (unsigned short*)allocB(BE*2);
    unsigned short* WT2c  = (unsigned short*)allocB((size_t)2048*768*2);
    unsigned short* WT2v  = (unsigned short*)allocB((size_t)2048*768*2);
    unsigned short* WsT   = (unsigned short*)allocB((size_t)4*H_DIM*H_DIM*2);
    unsigned short* Wp0Tc = (unsigned short*)allocB((size_t)P0_DIM*H_DIM*2);
    unsigned short* Wp0Tv = (unsigned short*)allocB((size_t)P0_DIM*H_DIM*2);
    unsigned short* Wp1Tc = (unsigned short*)allocB((size_t)P1_DIM*P0_DIM*2);
    unsigned short* Wp1Tv = (unsigned short*)allocB((size_t)P1_DIM*P0_DIM*2);
    unsigned short* Hc[2], *Hv[2];
    Hc[0] = (unsigned short*)allocB(BH*2);
    Hc[1] = (unsigned short*)allocB(BH*2);
    Hv[0] = (unsigned short*)allocB(BH*2);
    Hv[1] = (unsigned short*)allocB(BH*2);
    float* sc    = (float*)allocB(BH*4);
    float* sv    = (float*)allocB(BH*4);
    float* hv32  = (float*)allocB(BH*4);
    float* gbuf[2];
    gbuf[0] = (float*)allocB(BATCH*4);
    gbuf[1] = (float*)allocB(BATCH*4);

    const dim3 thr(256);
    const size_t HH = (size_t)H_DIM * H_DIM;

    // ---- one-time weight conversion ----
    k_wcat<<<dim3(3, 2048), thr, 0, stream>>>(Wx_c, Wh_c, WT2c);
    k_wcat<<<dim3(3, 2048), thr, 0, stream>>>(Wx_v, Wh_v, WT2v);
    for (int i = 0; i < 4; ++i)
        k_trans<<<dim3(2, 512), thr, 0, stream>>>(Ws + i*HH, WsT + i*HH, H_DIM, H_DIM);
    k_trans<<<dim3(2, 256), thr, 0, stream>>>(Wpc0, Wp0Tc, H_DIM, P0_DIM);
    k_trans<<<dim3(2, 256), thr, 0, stream>>>(Wpv0, Wp0Tv, H_DIM, P0_DIM);
    k_trans<<<dim3(1, 128), thr, 0, stream>>>(Wpc1, Wp1Tc, P0_DIM, P1_DIM);
    k_trans<<<dim3(1, 128), thr, 0, stream>>>(Wpv1, Wp1Tv, P0_DIM, P1_DIM);

    // ---- init: zero states; g0 = predict_c(zeros) -> gbuf[0]; convert x(0) ----
    k_init<<<4096, thr, 0, stream>>>(sc, sv, hv32, Hc[0], Hv[0]);
    k_predict_g<<<64, thr, 0, stream>>>(Hc[0], Wp0Tc, bpc0, Wp1Tc, bpc1, Wfcc, bfcc,
                                        gbuf[0], nullptr, nullptr);
    k_xcvt_g<<<128, thr, 0, stream>>>(inputs, Xh[0]);

    for (int t = 0; t < T_STEPS; ++t){
        const int cur = t & 1, nxt = cur ^ 1;

        // LA: fused click stream (gates_c + a1 + a2 + cell_c)
        k_fused<<<256, thr, 0, stream>>>(Xh[cur], Hc[cur], Hv[cur],
                                         WT2c, bx_c,
                                         WsT + 0*HH,   // Ws0 -> extraH = a1
                                         WsT + 1*HH,   // Ws1 -> extraV = a2
                                         gbuf[cur], sc, nullptr, Hc[nxt], 0);

        // LB: predict_c (g_new) + predict_v(t-1) (g_old) + xcvt(t+1)
        k_LB<<<256, thr, 0, stream>>>(Hc[nxt], Wp0Tc, bpc0, Wp1Tc, bpc1, Wfcc, bfcc,
                                      gbuf[nxt], out + (size_t)t*BATCH,
                                      Hv[cur], Wp0Tv, bpv0, Wp1Tv, bpv1, Wfcv, bfcv,
                                      gbuf[cur],
                                      (t > 0) ? out + (size_t)(T_STEPS + t - 1)*BATCH
                                              : nullptr,
                                      inputs + (size_t)(t+1)*BE,
                                      (t + 1 < T_STEPS) ? Xh[nxt] : nullptr);

        // LC: fused conversion stream (gates_v + a2v + a1v + cell_v)
        k_fused<<<256, thr, 0, stream>>>(Xh[cur], Hc[nxt], Hv[cur],
                                         WT2v, bx_v,
                                         WsT + 3*HH,   // Ws3 -> extraH = a2v
                                         WsT + 2*HH,   // Ws2 -> extraV = a1v
                                         gbuf[nxt], sv, hv32, Hv[nxt], 1);
    }
    // tail: pred_v(T-1); Hv_new(199)=Hv[0], g_new(199)=gbuf[0]
    k_predict_g<<<64, thr, 0, stream>>>(Hv[0], Wp0Tv, bpv0, Wp1Tv, bpv1, Wfcv, bfcv,
                                        nullptr, gbuf[0],
                                        out + (size_t)(2*T_STEPS - 1)*BATCH);
}

// Round 14
// 10474.024 us; speedup vs baseline: 1.5176x; 1.4053x over previous
//
#include <hip/hip_runtime.h>
#include <cstdint>
#include <cstddef>

constexpr int T_STEPS = 200;
constexpr int BATCH   = 2048;
constexpr int E_DIM   = 256;
constexpr int H_DIM   = 512;
constexpr int P0_DIM  = 256;
constexpr int P1_DIM  = 128;
constexpr float ALPHA = 0.3f;

typedef __attribute__((ext_vector_type(8))) _Float16 f16x8;
typedef __attribute__((ext_vector_type(4))) float f32x4;

__device__ __forceinline__ float sigmoidf_(float x){ return 1.0f/(1.0f+expf(-x)); }

__device__ __forceinline__ unsigned short f2h(float f){
    union { _Float16 h; unsigned short u; } v;
    v.h = (_Float16)f;                 // v_cvt_f16_f32, RNE
    return v.u;
}

#define GLOAD16(gp, lp) __builtin_amdgcn_global_load_lds( \
    (const __attribute__((address_space(1))) unsigned int*)(gp), \
    (__attribute__((address_space(3))) unsigned int*)(lp), 16, 0, 0)

// Stage a [ROWS][64] 16-bit tile into linear LDS, slot-swizzled at the SOURCE
// (m173 pattern): LDS[r][s] holds global k-slot (s ^ (r&7)) of row r.
template<int ROWS>
__device__ __forceinline__ void stage64(const unsigned short* __restrict__ src, int ldk,
                                        char* ldsbase){
    constexpr int TOT = ROWS * 8;          // 16B slots
    const int tid = threadIdx.x;
#pragma unroll
    for (int i = 0; i < TOT/256; ++i){
        const int gsl = i*256 + tid;
        const int r = gsl >> 3, s = gsl & 7;
        const int ksrc = ((s ^ (r & 7)) << 3);
        GLOAD16(src + (size_t)r*ldk + ksrc, ldsbase + gsl*16);
    }
}

// Swizzled b128 fragment read: row-stride 128B (BK=64), kslot in [0,8).
__device__ __forceinline__ f16x8 ldsfragh(const char* ldsbase, int row, int kslot){
    return *(const f16x8*)(ldsbase + row*128 + ((kslot ^ (row & 7)) << 4));
}

// ---------------------------------------------------------------------------
// Fused-phase K loop (double-buffered, counted vmcnt — r7-verified structure).
// A: 64 rows. B1 (optional): 128 rows (gates panel). B2 (optional): 32 rows.
// Per-buf layout: A at +0 (8KB), B1 at +8192 (16KB), B2 at +24576 (4KB);
// bufs at 0 / 32768.
// accg: gates acc (wave covers rows wr*32+[0,32), cols wc*64+[0,64)).
// acce: extra acc (wave covers rows wr*32+[0,32), cols wc*16+[0,16)).
// ---------------------------------------------------------------------------
template<bool HAS_B1, bool HAS_B2, int KSLABS>
__device__ __forceinline__ void fused_phase(
    const unsigned short* __restrict__ A, int lda,
    const unsigned short* __restrict__ B1,
    const unsigned short* __restrict__ B2,
    f32x4 (&accg)[2][4], f32x4 (&acce)[2],
    char* lds, int wr, int wc, int lr, int lq)
{
    stage64<64>(A, lda, lds);
    if (HAS_B1) stage64<128>(B1, 768, lds + 8192);
    if (HAS_B2) stage64<32>(B2, 512, lds + 24576);
    int cur = 0;
    for (int s = 0; s < KSLABS; ++s){
        char* bufc = lds + cur*32768;
        if (s + 1 < KSLABS){
            char* bufn = lds + (cur^1)*32768;
            stage64<64>(A + (s+1)*64, lda, bufn);
            if (HAS_B1) stage64<128>(B1 + (s+1)*64, 768, bufn + 8192);
            if (HAS_B2) stage64<32>(B2 + (s+1)*64, 512, bufn + 24576);
            if constexpr (HAS_B1 && HAS_B2)
                asm volatile("s_waitcnt vmcnt(7)" ::: "memory");
            else if constexpr (HAS_B1)
                asm volatile("s_waitcnt vmcnt(6)" ::: "memory");
            else
                asm volatile("s_waitcnt vmcnt(3)" ::: "memory");
        } else {
            asm volatile("s_waitcnt vmcnt(0)" ::: "memory");
        }
        __builtin_amdgcn_s_barrier();
        __builtin_amdgcn_sched_barrier(0);
        __builtin_amdgcn_s_setprio(1);
#pragma unroll
        for (int kk = 0; kk < 2; ++kk){
            f16x8 a[2];
#pragma unroll
            for (int m = 0; m < 2; ++m) a[m] = ldsfragh(bufc, wr*32 + m*16 + lr, kk*4 + lq);
            if (HAS_B1){
#pragma unroll
                for (int n = 0; n < 4; ++n){
                    f16x8 b = ldsfragh(bufc + 8192, wc*64 + n*16 + lr, kk*4 + lq);
#pragma unroll
                    for (int m = 0; m < 2; ++m)
                        accg[m][n] = __builtin_amdgcn_mfma_f32_16x16x32_f16(a[m], b, accg[m][n], 0,0,0);
                }
            }
            if (HAS_B2){
                f16x8 b = ldsfragh(bufc + 24576, wc*16 + lr, kk*4 + lq);
#pragma unroll
                for (int m = 0; m < 2; ++m)
                    acce[m] = __builtin_amdgcn_mfma_f32_16x16x32_f16(a[m], b, acce[m], 0,0,0);
            }
        }
        __builtin_amdgcn_s_setprio(0);
        __builtin_amdgcn_sched_barrier(0);
        __builtin_amdgcn_s_barrier();
        cur ^= 1;
    }
}

// ---------------------------------------------------------------------------
// Fused stream kernel: 512 blocks = 32 brow-groups x 16 h-groups.
//   gates(64x128, K=768: X then AH) + extraH(64x32 = AH@WsH, K=512)
//   + extraV(64x32 = AV@WsV, K=512) + inline cell update.
// mode 0 (click): a1=extraH(Hc@Ws0), a2=extraV(Hv@Ws1); writes sc, Hc_new.
// mode 1 (conv):  a1=extraV(Hv@Ws2), a2=extraH(Hc@Ws3); writes sv, hv32, Hv_new.
// WT2 layout: [2048][768], n' = (h/32)*128 + z*32 + (h%32).
// ---------------------------------------------------------------------------
__global__ __launch_bounds__(256, 2) void k_fused(
    const unsigned short* __restrict__ Xh,
    const unsigned short* __restrict__ AH,   // Hc_old (mode 0) / Hc_new (mode 1)
    const unsigned short* __restrict__ AV,   // Hv_old
    const unsigned short* __restrict__ WT2,
    const float* __restrict__ bias,          // [4][512] z-major
    const unsigned short* __restrict__ WsH,  // Ws0 (mode 0) / Ws3 (mode 1)
    const unsigned short* __restrict__ WsV,  // Ws1 (mode 0) / Ws2 (mode 1)
    const float* __restrict__ g,
    float* __restrict__ sstate, float* __restrict__ Hv32,
    unsigned short* __restrict__ Hnew,
    const int mode)
{
    __shared__ __align__(16) char lds[65536];
    const int tid = threadIdx.x;
    const int lane = tid & 63, wid = tid >> 6;
    const int wr = wid >> 1, wc = wid & 1;
    const int lr = lane & 15, lq = lane >> 4;

    // XCD-bijective swizzle: XCD k gets hgrps {2k,2k+1} with all 32 brow-groups.
    const int id = blockIdx.x;
    const int virt = ((id & 7) << 6) | (id >> 3);
    const int hgrp = virt >> 5;      // 0..15
    const int brow = (virt & 31) * 64;
    const int h0   = hgrp * 32;

    f32x4 accg[2][4], acceH[2], acceV[2];
#pragma unroll
    for (int m = 0; m < 2; ++m){
        f32x4 z = {0.f,0.f,0.f,0.f};
#pragma unroll
        for (int n = 0; n < 4; ++n) accg[m][n] = z;
        acceH[m] = z; acceV[m] = z;
    }

    const unsigned short* WTp = WT2 + (size_t)hgrp*128*768;
    // phase X: gates k 0..255
    fused_phase<true,false,4>(Xh + (size_t)brow*E_DIM, E_DIM, WTp, nullptr,
                              accg, acceH, lds, wr, wc, lr, lq);
    // phase H: gates k 256..767 + extraH k 0..511
    fused_phase<true,true,8>(AH + (size_t)brow*H_DIM, H_DIM, WTp + E_DIM,
                             WsH + (size_t)h0*H_DIM,
                             accg, acceH, lds, wr, wc, lr, lq);
    // phase V: extraV k 0..511
    fused_phase<false,true,8>(AV + (size_t)brow*H_DIM, H_DIM, nullptr,
                              WsV + (size_t)h0*H_DIM,
                              accg, acceV, lds, wr, wc, lr, lq);

    // ---- epilogue: gates (activated) + extras (raw) -> LDS (padded) ----
    float* ldsG  = (float*)lds;               // [64][132] fp32 (pad +4)
    float* ldsEH = (float*)(lds + 33792);     // [64][33]
    float* ldsEV = (float*)(lds + 42240);     // [64][33]
#pragma unroll
    for (int m = 0; m < 2; ++m){
#pragma unroll
        for (int n = 0; n < 4; ++n){
            const int col = wc*64 + n*16 + lr;          // 0..127 = z*32 + hl
            const int z = col >> 5, hl = col & 31;
            const float bs = bias[z*H_DIM + h0 + hl];
#pragma unroll
            for (int r = 0; r < 4; ++r){
                const int row = wr*32 + m*16 + lq*4 + r;
                float v = accg[m][n][r] + bs;
                v = (z < 3) ? sigmoidf_(v) : tanhf(v);
                ldsG[row*132 + col] = v;
            }
        }
    }
#pragma unroll
    for (int m = 0; m < 2; ++m){
        const int col = wc*16 + lr;                     // 0..31
#pragma unroll
        for (int r = 0; r < 4; ++r){
            const int row = wr*32 + m*16 + lq*4 + r;
            ldsEH[row*33 + col] = acceH[m][r];
            ldsEV[row*33 + col] = acceV[m][r];
        }
    }
    __syncthreads();

    // ---- inline cell: 256 threads x 8 elems ----
    const int crow = tid >> 2, ch = (tid & 3) * 8;
    const int grow = brow + crow;
    const float gv = g[grow];
    const size_t gbase = (size_t)grow*H_DIM + h0 + ch;
    union U4 { float4 v; float s[4]; };
    U4 sv0, sv1, hv0, hv1;
    sv0.v = *(const float4*)&sstate[gbase];
    sv1.v = *(const float4*)&sstate[gbase + 4];
    if (mode == 1){
        hv0.v = *(const float4*)&Hv32[gbase];
        hv1.v = *(const float4*)&Hv32[gbase + 4];
    }
    U4 sn0, sn1, hn0, hn1;
    union { unsigned short u[8]; f16x8 v; } hh;
#pragma unroll
    for (int e = 0; e < 8; ++e){
        const int hc = ch + e;
        const float f_ = ldsG[crow*132 + hc];
        const float i_ = ldsG[crow*132 + 32 + hc];
        const float o_ = ldsG[crow*132 + 64 + hc];
        const float q_ = ldsG[crow*132 + 96 + hc];
        const float eh = ldsEH[crow*33 + hc];
        const float ev = ldsEV[crow*33 + hc];
        const float a1 = (mode == 0) ? eh : ev;
        const float a2 = (mode == 0) ? ev : eh;
        const float svo = (e < 4) ? sv0.s[e] : sv1.s[e-4];
        float s, hval;
        if (mode == 0){
            const float shat = tanhf((1.0f - gv)*a1 + gv*a2);
            s = shat + i_*q_ + (1.0f - gv)*(f_*svo);
            hval = o_ * tanhf(s);
        } else {
            const float shat = tanhf(a1 + gv*a2);
            s = shat + (1.0f - gv)*svo + gv*(f_*svo + i_*q_);
            const float hvo = (e < 4) ? hv0.s[e] : hv1.s[e-4];
            hval = (1.0f - gv)*hvo + gv*(o_*tanhf(s));
            if (e < 4) hn0.s[e] = hval; else hn1.s[e-4] = hval;
        }
        if (e < 4) sn0.s[e] = s; else sn1.s[e-4] = s;
        hh.u[e] = f2h(hval);
    }
    *(float4*)&sstate[gbase]     = sn0.v;
    *(float4*)&sstate[gbase + 4] = sn1.v;
    if (mode == 1){
        *(float4*)&Hv32[gbase]     = hn0.v;
        *(float4*)&Hv32[gbase + 4] = hn1.v;
    }
    *(f16x8*)&Hnew[gbase] = hh.v;
}

// ---------------------------------------------------------------------------
// Predict (32 rows per pblk): p0=leaky(H@W0+b0), p1=leaky(p0@W1+b1),
// val=sigmoid(dot(p1,Wf)+bf) (*gmul). Verified rounds 3-10.
// ---------------------------------------------------------------------------
__device__ __forceinline__ void predict_dev(
    int pblk, const unsigned short* __restrict__ Hh,
    const unsigned short* __restrict__ W0T, const float* __restrict__ b0,
    const unsigned short* __restrict__ W1T, const float* __restrict__ b1,
    const float* __restrict__ Wf, const float* __restrict__ bf_,
    float* gstate, const float* __restrict__ gmul, float* pred, char* lds)
{
    char*  ldsA = lds;                    // [32][128B]
    char*  ldsB = lds + 4096;             // up to [256][128B]
    char*  ldsP = lds + 36864;            // [32][512B] p0 fp16 (swizzled)
    float* sums = (float*)(lds + 53248);  // [4][32]
    const int tid = threadIdx.x, lane = tid & 63, w = tid >> 6;
    const int lr = lane & 15, lq = lane >> 4;
    const int brow = pblk * 32;

    f32x4 acc0[2][4];
#pragma unroll
    for (int m = 0; m < 2; ++m)
#pragma unroll
        for (int n = 0; n < 4; ++n){ f32x4 z = {0.f,0.f,0.f,0.f}; acc0[m][n] = z; }

    for (int k0 = 0; k0 < H_DIM; k0 += 64){
        stage64<32>(Hh + (size_t)brow*H_DIM + k0, H_DIM, ldsA);
        stage64<256>(W0T + k0, H_DIM, ldsB);
        __syncthreads();
#pragma unroll
        for (int kk = 0; kk < 2; ++kk){
            f16x8 a[2], b[4];
#pragma unroll
            for (int m = 0; m < 2; ++m) a[m] = ldsfragh(ldsA, m*16 + lr, kk*4 + lq);
#pragma unroll
            for (int n = 0; n < 4; ++n) b[n] = ldsfragh(ldsB, w*64 + n*16 + lr, kk*4 + lq);
#pragma unroll
            for (int m = 0; m < 2; ++m)
#pragma unroll
                for (int n = 0; n < 4; ++n)
                    acc0[m][n] = __builtin_amdgcn_mfma_f32_16x16x32_f16(a[m], b[n], acc0[m][n], 0,0,0);
        }
        __syncthreads();
    }
#pragma unroll
    for (int m = 0; m < 2; ++m){
#pragma unroll
        for (int n = 0; n < 4; ++n){
            const int col = w*64 + n*16 + lr;
            const float bs = b0[col];
#pragma unroll
            for (int r = 0; r < 4; ++r){
                const int row = m*16 + lq*4 + r;
                float x = acc0[m][n][r] + bs;
                x = (x > 0.0f) ? x : ALPHA*x;
                *(unsigned short*)(ldsP + row*512 + ((((col >> 3)) ^ (row & 7)) << 4) + (col & 7)*2) = f2h(x);
            }
        }
    }
    __syncthreads();

    f32x4 accp[2][2];
#pragma unroll
    for (int m = 0; m < 2; ++m)
#pragma unroll
        for (int n = 0; n < 2; ++n){ f32x4 z = {0.f,0.f,0.f,0.f}; accp[m][n] = z; }

    for (int k0 = 0; k0 < P0_DIM; k0 += 64){
        stage64<128>(W1T + k0, P0_DIM, ldsB);
        __syncthreads();
#pragma unroll
        for (int kk = 0; kk < 2; ++kk){
            f16x8 a[2], b[2];
#pragma unroll
            for (int m = 0; m < 2; ++m){
                const int row = m*16 + lr;
                const int slot = (k0 >> 3) + kk*4 + lq;
                a[m] = *(const f16x8*)(ldsP + row*512 + ((slot ^ (row & 7)) << 4));
            }
#pragma unroll
            for (int n = 0; n < 2; ++n) b[n] = ldsfragh(ldsB, w*32 + n*16 + lr, kk*4 + lq);
#pragma unroll
            for (int m = 0; m < 2; ++m)
#pragma unroll
                for (int n = 0; n < 2; ++n)
                    accp[m][n] = __builtin_amdgcn_mfma_f32_16x16x32_f16(a[m], b[n], accp[m][n], 0,0,0);
        }
        __syncthreads();
    }

    float part[8];
#pragma unroll
    for (int j = 0; j < 8; ++j) part[j] = 0.0f;
#pragma unroll
    for (int m = 0; m < 2; ++m){
#pragma unroll
        for (int n = 0; n < 2; ++n){
            const int col = w*32 + n*16 + lr;
            const float bs = b1[col], wf = Wf[col];
#pragma unroll
            for (int r = 0; r < 4; ++r){
                float x = accp[m][n][r] + bs;
                x = (x > 0.0f) ? x : ALPHA*x;
                part[m*4 + r] += x * wf;
            }
        }
    }
#pragma unroll
    for (int mask = 1; mask < 16; mask <<= 1)
#pragma unroll
        for (int j = 0; j < 8; ++j) part[j] += __shfl_xor(part[j], mask);
    if (lr == 0){
#pragma unroll
        for (int j = 0; j < 8; ++j){
            const int row = (j >> 2)*16 + lq*4 + (j & 3);
            sums[w*32 + row] = part[j];
        }
    }
    __syncthreads();
    if (tid < 32){
        float tot = sums[tid] + sums[32 + tid] + sums[64 + tid] + sums[96 + tid] + bf_[0];
        float val = sigmoidf_(tot);
        const int rowg = brow + tid;
        if (gmul)   val *= gmul[rowg];
        if (gstate) gstate[rowg] = val;
        if (pred)   pred[rowg]   = val;
    }
}

// x-step fp16 convert: 128 blocks x 256 thr x 4 float4.
__device__ __forceinline__ void xcvt_dev(int blk, const float* __restrict__ x,
                                         unsigned short* __restrict__ oh)
{
    const int tid = threadIdx.x;
#pragma unroll
    for (int j = 0; j < 4; ++j){
        const int t = blk*256 + tid + j*32768;
        float4 v = ((const float4*)x)[t];
        ushort4 h;
        h.x = f2h(v.x); h.y = f2h(v.y); h.z = f2h(v.z); h.w = f2h(v.w);
        ((ushort4*)oh)[t] = h;
    }
}

// ---------------------------------------------------------------------------
// LB: [0,64) predict_c (writes gnew, pred_c) | [64,128) predict_v(t-1) reads gold
//     | [128,256) xcvt(t+1)
// ---------------------------------------------------------------------------
__global__ __launch_bounds__(256) void k_LB(
    const unsigned short* __restrict__ Hcn,
    const unsigned short* __restrict__ Wp0Tc, const float* __restrict__ bpc0,
    const unsigned short* __restrict__ Wp1Tc, const float* __restrict__ bpc1,
    const float* __restrict__ Wfcc, const float* __restrict__ bfcc,
    float* __restrict__ gnew, float* __restrict__ predc,
    const unsigned short* __restrict__ Hvb,
    const unsigned short* __restrict__ Wp0Tv, const float* __restrict__ bpv0,
    const unsigned short* __restrict__ Wp1Tv, const float* __restrict__ bpv1,
    const float* __restrict__ Wfcv, const float* __restrict__ bfcv,
    const float* __restrict__ gold, float* __restrict__ predv,
    const float* __restrict__ xnext, unsigned short* __restrict__ Xnh)
{
    __shared__ __align__(16) char lds[53760];
    const int id = blockIdx.x;
    if (id < 64){
        predict_dev(id, Hcn, Wp0Tc, bpc0, Wp1Tc, bpc1, Wfcc, bfcc,
                    gnew, nullptr, predc, lds);
    } else if (id < 128){
        if (predv) predict_dev(id - 64, Hvb, Wp0Tv, bpv0, Wp1Tv, bpv1, Wfcv, bfcv,
                               nullptr, gold, predv, lds);
    } else {
        if (Xnh) xcvt_dev(id - 128, xnext, Xnh);
    }
}

// ---------------------------------------------------------------------------
// Standalone predict (init g0 / final pred_v) and x0 convert.
// ---------------------------------------------------------------------------
__global__ __launch_bounds__(256) void k_predict_g(
    const unsigned short* __restrict__ Hh,
    const unsigned short* __restrict__ W0T, const float* __restrict__ b0,
    const unsigned short* __restrict__ W1T, const float* __restrict__ b1,
    const float* __restrict__ Wf, const float* __restrict__ bf_,
    float* gstate, const float* __restrict__ gmul, float* pred)
{
    __shared__ __align__(16) char lds[53760];
    predict_dev(blockIdx.x, Hh, W0T, b0, W1T, b1, Wf, bf_, gstate, gmul, pred, lds);
}

__global__ __launch_bounds__(256) void k_xcvt_g(const float* __restrict__ x,
                                                unsigned short* __restrict__ oh)
{
    xcvt_dev(blockIdx.x, x, oh);
}

// ---------------------------------------------------------------------------
// Prep kernels. WT2 layout: n' = (h/32)*128 + z*32 + (h%32), k in [0,768).
// ---------------------------------------------------------------------------
__global__ __launch_bounds__(256) void k_wcat(const float* __restrict__ Wx,
                                              const float* __restrict__ Wh,
                                              unsigned short* __restrict__ oh){
    const int n = blockIdx.y;                 // n' in [0,2048)
    const int k = blockIdx.x*256 + threadIdx.x;
    const int z = (n >> 5) & 3;
    const int h = ((n >> 7) << 5) | (n & 31);
    float v = (k < 256) ? Wx[((size_t)z*E_DIM + k)*H_DIM + h]
                        : Wh[((size_t)z*H_DIM + (k - 256))*H_DIM + h];
    oh[(size_t)n*768 + k] = f2h(v);
}

__global__ __launch_bounds__(256) void k_trans(const float* __restrict__ in,
                                               unsigned short* __restrict__ oh,
                                               int K, int N){
    const int k = blockIdx.x*256 + threadIdx.x;
    const int n = blockIdx.y;
    if (k < K) oh[(size_t)n*K + k] = f2h(in[(size_t)k*N + n]);
}

__global__ __launch_bounds__(256) void k_init(float* __restrict__ sc, float* __restrict__ sv,
                                              float* __restrict__ hv32,
                                              unsigned short* __restrict__ hc0,
                                              unsigned short* __restrict__ hv0){
    const int i = blockIdx.x*256 + threadIdx.x;
    sc[i] = 0.0f; sv[i] = 0.0f; hv32[i] = 0.0f;
    hc0[i] = 0; hv0[i] = 0;
}

// ---------------------------------------------------------------------------
extern "C" void kernel_launch(void* const* d_in, const int* in_sizes, int n_in,
                              void* d_out, int out_size, void* d_ws, size_t ws_size,
                              hipStream_t stream)
{
    (void)in_sizes; (void)n_in; (void)out_size; (void)ws_size;

    const float* inputs = (const float*)d_in[0];
    const float* Wx_c   = (const float*)d_in[1];
    const float* bx_c   = (const float*)d_in[2];
    const float* Wh_c   = (const float*)d_in[3];
    const float* Wx_v   = (const float*)d_in[4];
    const float* bx_v   = (const float*)d_in[5];
    const float* Wh_v   = (const float*)d_in[6];
    const float* Ws     = (const float*)d_in[7];
    const float* Wpc0   = (const float*)d_in[8];
    const float* bpc0   = (const float*)d_in[9];
    const float* Wpc1   = (const float*)d_in[10];
    const float* bpc1   = (const float*)d_in[11];
    const float* Wfcc   = (const float*)d_in[12];
    const float* bfcc   = (const float*)d_in[13];
    const float* Wpv0   = (const float*)d_in[14];
    const float* bpv0   = (const float*)d_in[15];
    const float* Wpv1   = (const float*)d_in[16];
    const float* bpv1   = (const float*)d_in[17];
    const float* Wfcv   = (const float*)d_in[18];
    const float* bfcv   = (const float*)d_in[19];
    float* out = (float*)d_out;

    char* ws = (char*)d_ws;
    size_t off = 0;
    auto allocB = [&](size_t bytes) -> char* {
        char* p = ws + off;
        off = (off + bytes + 255) & ~(size_t)255;
        return p;
    };
    const size_t BH = (size_t)BATCH * H_DIM;
    const size_t BE = (size_t)BATCH * E_DIM;

    unsigned short* Xh[2];
    Xh[0] = (unsigned short*)allocB(BE*2);
    Xh[1] = (unsigned short*)allocB(BE*2);
    unsigned short* WT2c  = (unsigned short*)allocB((size_t)2048*768*2);
    unsigned short* WT2v  = (unsigned short*)allocB((size_t)2048*768*2);
    unsigned short* WsT   = (unsigned short*)allocB((size_t)4*H_DIM*H_DIM*2);
    unsigned short* Wp0Tc = (unsigned short*)allocB((size_t)P0_DIM*H_DIM*2);
    unsigned short* Wp0Tv = (unsigned short*)allocB((size_t)P0_DIM*H_DIM*2);
    unsigned short* Wp1Tc = (unsigned short*)allocB((size_t)P1_DIM*P0_DIM*2);
    unsigned short* Wp1Tv = (unsigned short*)allocB((size_t)P1_DIM*P0_DIM*2);
    unsigned short* Hc[2], *Hv[2];
    Hc[0] = (unsigned short*)allocB(BH*2);
    Hc[1] = (unsigned short*)allocB(BH*2);
    Hv[0] = (unsigned short*)allocB(BH*2);
    Hv[1] = (unsigned short*)allocB(BH*2);
    float* sc    = (float*)allocB(BH*4);
    float* sv    = (float*)allocB(BH*4);
    float* hv32  = (float*)allocB(BH*4);
    float* gbuf[2];
    gbuf[0] = (float*)allocB(BATCH*4);
    gbuf[1] = (float*)allocB(BATCH*4);

    const dim3 thr(256);
    const size_t HH = (size_t)H_DIM * H_DIM;

    // ---- one-time weight conversion ----
    k_wcat<<<dim3(3, 2048), thr, 0, stream>>>(Wx_c, Wh_c, WT2c);
    k_wcat<<<dim3(3, 2048), thr, 0, stream>>>(Wx_v, Wh_v, WT2v);
    for (int i = 0; i < 4; ++i)
        k_trans<<<dim3(2, 512), thr, 0, stream>>>(Ws + i*HH, WsT + i*HH, H_DIM, H_DIM);
    k_trans<<<dim3(2, 256), thr, 0, stream>>>(Wpc0, Wp0Tc, H_DIM, P0_DIM);
    k_trans<<<dim3(2, 256), thr, 0, stream>>>(Wpv0, Wp0Tv, H_DIM, P0_DIM);
    k_trans<<<dim3(1, 128), thr, 0, stream>>>(Wpc1, Wp1Tc, P0_DIM, P1_DIM);
    k_trans<<<dim3(1, 128), thr, 0, stream>>>(Wpv1, Wp1Tv, P0_DIM, P1_DIM);

    // ---- init: zero states; g0 = predict_c(zeros) -> gbuf[0]; convert x(0) ----
    k_init<<<4096, thr, 0, stream>>>(sc, sv, hv32, Hc[0], Hv[0]);
    k_predict_g<<<64, thr, 0, stream>>>(Hc[0], Wp0Tc, bpc0, Wp1Tc, bpc1, Wfcc, bfcc,
                                        gbuf[0], nullptr, nullptr);
    k_xcvt_g<<<128, thr, 0, stream>>>(inputs, Xh[0]);

    for (int t = 0; t < T_STEPS; ++t){
        const int cur = t & 1, nxt = cur ^ 1;

        // LA: fused click stream (gates_c + a1 + a2 + cell_c)
        k_fused<<<512, thr, 0, stream>>>(Xh[cur], Hc[cur], Hv[cur],
                                         WT2c, bx_c,
                                         WsT + 0*HH,   // Ws0 -> extraH = a1
                                         WsT + 1*HH,   // Ws1 -> extraV = a2
                                         gbuf[cur], sc, nullptr, Hc[nxt], 0);

        // LB: predict_c (g_new) + predict_v(t-1) (g_old) + xcvt(t+1)
        k_LB<<<256, thr, 0, stream>>>(Hc[nxt], Wp0Tc, bpc0, Wp1Tc, bpc1, Wfcc, bfcc,
                                      gbuf[nxt], out + (size_t)t*BATCH,
                                      Hv[cur], Wp0Tv, bpv0, Wp1Tv, bpv1, Wfcv, bfcv,
                                      gbuf[cur],
                                      (t > 0) ? out + (size_t)(T_STEPS + t - 1)*BATCH
                                              : nullptr,
                                      inputs + (size_t)(t+1)*BE,
                                      (t + 1 < T_STEPS) ? Xh[nxt] : nullptr);

        // LC: fused conversion stream (gates_v + a2v + a1v + cell_v)
        k_fused<<<512, thr, 0, stream>>>(Xh[cur], Hc[nxt], Hv[cur],
                                         WT2v, bx_v,
                                         WsT + 3*HH,   // Ws3 -> extraH = a2v
                                         WsT + 2*HH,   // Ws2 -> extraV = a1v
                                         gbuf[nxt], sv, hv32, Hv[nxt], 1);
    }
    // tail: pred_v(T-1); Hv_new(199)=Hv[0], g_new(199)=gbuf[0]
    k_predict_g<<<64, thr, 0, stream>>>(Hv[0], Wp0Tv, bpv0, Wp1Tv, bpv1, Wfcv, bfcv,
                                        nullptr, gbuf[0],
                                        out + (size_t)(2*T_STEPS - 1)*BATCH);
}

// Round 15
// 9832.416 us; speedup vs baseline: 1.6167x; 1.0653x over previous
//
#include <hip/hip_runtime.h>
#include <cstdint>
#include <cstddef>

constexpr int T_STEPS = 200;
constexpr int BATCH   = 2048;
constexpr int E_DIM   = 256;
constexpr int H_DIM   = 512;
constexpr int P0_DIM  = 256;
constexpr int P1_DIM  = 128;
constexpr float ALPHA = 0.3f;

typedef __attribute__((ext_vector_type(8))) _Float16 f16x8;
typedef __attribute__((ext_vector_type(4))) float f32x4;

__device__ __forceinline__ float sigmoidf_(float x){ return 1.0f/(1.0f+expf(-x)); }

__device__ __forceinline__ unsigned short f2h(float f){
    union { _Float16 h; unsigned short u; } v;
    v.h = (_Float16)f;                 // v_cvt_f16_f32, RNE
    return v.u;
}

#define GLOAD16(gp, lp) __builtin_amdgcn_global_load_lds( \
    (const __attribute__((address_space(1))) unsigned int*)(gp), \
    (__attribute__((address_space(3))) unsigned int*)(lp), 16, 0, 0)

// Stage a [ROWS][64] 16-bit tile into linear LDS, slot-swizzled at the SOURCE
// (m173 pattern): LDS[r][s] holds global k-slot (s ^ (r&7)) of row r.
template<int ROWS>
__device__ __forceinline__ void stage64(const unsigned short* __restrict__ src, int ldk,
                                        char* ldsbase){
    constexpr int TOT = ROWS * 8;          // 16B slots
    const int tid = threadIdx.x;
#pragma unroll
    for (int i = 0; i < TOT/256; ++i){
        const int gsl = i*256 + tid;
        const int r = gsl >> 3, s = gsl & 7;
        const int ksrc = ((s ^ (r & 7)) << 3);
        GLOAD16(src + (size_t)r*ldk + ksrc, ldsbase + gsl*16);
    }
}

// Swizzled b128 fragment read: row-stride 128B (BK=64), kslot in [0,8).
__device__ __forceinline__ f16x8 ldsfragh(const char* ldsbase, int row, int kslot){
    return *(const f16x8*)(ldsbase + row*128 + ((kslot ^ (row & 7)) << 4));
}

// ---------------------------------------------------------------------------
// Fused-phase K loop (double-buffered, counted vmcnt — r7-verified structure).
// A: 64 rows. B1 (optional): 128 rows (gates panel). B2 (optional): 32 rows.
// Per-buf layout: A at +0 (8KB), B1 at +8192 (16KB), B2 at +24576 (4KB);
// bufs at 0 / 32768.
// accg: gates acc (wave covers rows wr*32+[0,32), cols wc*64+[0,64)).
// acce: extra acc (wave covers rows wr*32+[0,32), cols wc*16+[0,16)).
// ---------------------------------------------------------------------------
template<bool HAS_B1, bool HAS_B2, int KSLABS>
__device__ __forceinline__ void fused_phase(
    const unsigned short* __restrict__ A, int lda,
    const unsigned short* __restrict__ B1,
    const unsigned short* __restrict__ B2,
    f32x4 (&accg)[2][4], f32x4 (&acce)[2],
    char* lds, int wr, int wc, int lr, int lq)
{
    stage64<64>(A, lda, lds);
    if (HAS_B1) stage64<128>(B1, 768, lds + 8192);
    if (HAS_B2) stage64<32>(B2, 512, lds + 24576);
    int cur = 0;
    for (int s = 0; s < KSLABS; ++s){
        char* bufc = lds + cur*32768;
        if (s + 1 < KSLABS){
            char* bufn = lds + (cur^1)*32768;
            stage64<64>(A + (s+1)*64, lda, bufn);
            if (HAS_B1) stage64<128>(B1 + (s+1)*64, 768, bufn + 8192);
            if (HAS_B2) stage64<32>(B2 + (s+1)*64, 512, bufn + 24576);
            if constexpr (HAS_B1 && HAS_B2)
                asm volatile("s_waitcnt vmcnt(7)" ::: "memory");
            else if constexpr (HAS_B1)
                asm volatile("s_waitcnt vmcnt(6)" ::: "memory");
            else
                asm volatile("s_waitcnt vmcnt(3)" ::: "memory");
        } else {
            asm volatile("s_waitcnt vmcnt(0)" ::: "memory");
        }
        __builtin_amdgcn_s_barrier();
        __builtin_amdgcn_sched_barrier(0);
        __builtin_amdgcn_s_setprio(1);
#pragma unroll
        for (int kk = 0; kk < 2; ++kk){
            f16x8 a[2];
#pragma unroll
            for (int m = 0; m < 2; ++m) a[m] = ldsfragh(bufc, wr*32 + m*16 + lr, kk*4 + lq);
            if (HAS_B1){
#pragma unroll
                for (int n = 0; n < 4; ++n){
                    f16x8 b = ldsfragh(bufc + 8192, wc*64 + n*16 + lr, kk*4 + lq);
#pragma unroll
                    for (int m = 0; m < 2; ++m)
                        accg[m][n] = __builtin_amdgcn_mfma_f32_16x16x32_f16(a[m], b, accg[m][n], 0,0,0);
                }
            }
            if (HAS_B2){
                f16x8 b = ldsfragh(bufc + 24576, wc*16 + lr, kk*4 + lq);
#pragma unroll
                for (int m = 0; m < 2; ++m)
                    acce[m] = __builtin_amdgcn_mfma_f32_16x16x32_f16(a[m], b, acce[m], 0,0,0);
            }
        }
        __builtin_amdgcn_s_setprio(0);
        __builtin_amdgcn_sched_barrier(0);
        __builtin_amdgcn_s_barrier();
        cur ^= 1;
    }
}

// ---------------------------------------------------------------------------
// Fused stream kernel: 512 blocks = 32 brow-groups x 16 h-groups.
//   gates(64x128, K=768: X then AH) + extraH(64x32 = AH@WsH, K=512)
//   + extraV(64x32 = AV@WsV, K=512) + inline cell update.
// mode 0 (click): a1=extraH(Hc@Ws0), a2=extraV(Hv@Ws1); writes sc, Hc_new.
// mode 1 (conv):  a1=extraV(Hv@Ws2), a2=extraH(Hc@Ws3); writes sv, hv32, Hv_new.
// WT2 layout: [2048][768], n' = (h/32)*128 + z*32 + (h%32).
// ---------------------------------------------------------------------------
__global__ __launch_bounds__(256, 2) void k_fused(
    const unsigned short* __restrict__ Xh,
    const unsigned short* __restrict__ AH,   // Hc_old (mode 0) / Hc_new (mode 1)
    const unsigned short* __restrict__ AV,   // Hv_old
    const unsigned short* __restrict__ WT2,
    const float* __restrict__ bias,          // [4][512] z-major
    const unsigned short* __restrict__ WsH,  // Ws0 (mode 0) / Ws3 (mode 1)
    const unsigned short* __restrict__ WsV,  // Ws1 (mode 0) / Ws2 (mode 1)
    const float* __restrict__ g,
    float* __restrict__ sstate, float* __restrict__ Hv32,
    unsigned short* __restrict__ Hnew,
    const int mode)
{
    __shared__ __align__(16) char lds[65536];
    const int tid = threadIdx.x;
    const int lane = tid & 63, wid = tid >> 6;
    const int wr = wid >> 1, wc = wid & 1;
    const int lr = lane & 15, lq = lane >> 4;

    // XCD-bijective swizzle: XCD k gets hgrps {2k,2k+1} with all 32 brow-groups.
    const int id = blockIdx.x;
    const int virt = ((id & 7) << 6) | (id >> 3);
    const int hgrp = virt >> 5;      // 0..15
    const int brow = (virt & 31) * 64;
    const int h0   = hgrp * 32;

    f32x4 accg[2][4], acceH[2], acceV[2];
#pragma unroll
    for (int m = 0; m < 2; ++m){
        f32x4 z = {0.f,0.f,0.f,0.f};
#pragma unroll
        for (int n = 0; n < 4; ++n) accg[m][n] = z;
        acceH[m] = z; acceV[m] = z;
    }

    const unsigned short* WTp = WT2 + (size_t)hgrp*128*768;
    // phase X: gates k 0..255
    fused_phase<true,false,4>(Xh + (size_t)brow*E_DIM, E_DIM, WTp, nullptr,
                              accg, acceH, lds, wr, wc, lr, lq);
    // phase H: gates k 256..767 + extraH k 0..511
    fused_phase<true,true,8>(AH + (size_t)brow*H_DIM, H_DIM, WTp + E_DIM,
                             WsH + (size_t)h0*H_DIM,
                             accg, acceH, lds, wr, wc, lr, lq);
    // phase V: extraV k 0..511
    fused_phase<false,true,8>(AV + (size_t)brow*H_DIM, H_DIM, nullptr,
                              WsV + (size_t)h0*H_DIM,
                              accg, acceV, lds, wr, wc, lr, lq);

    // ---- epilogue: gates (activated) + extras (raw) -> LDS (padded) ----
    float* ldsG  = (float*)lds;               // [64][132] fp32 (pad +4)
    float* ldsEH = (float*)(lds + 33792);     // [64][33]
    float* ldsEV = (float*)(lds + 42240);     // [64][33]
#pragma unroll
    for (int m = 0; m < 2; ++m){
#pragma unroll
        for (int n = 0; n < 4; ++n){
            const int col = wc*64 + n*16 + lr;          // 0..127 = z*32 + hl
            const int z = col >> 5, hl = col & 31;
            const float bs = bias[z*H_DIM + h0 + hl];
#pragma unroll
            for (int r = 0; r < 4; ++r){
                const int row = wr*32 + m*16 + lq*4 + r;
                float v = accg[m][n][r] + bs;
                v = (z < 3) ? sigmoidf_(v) : tanhf(v);
                ldsG[row*132 + col] = v;
            }
        }
    }
#pragma unroll
    for (int m = 0; m < 2; ++m){
        const int col = wc*16 + lr;                     // 0..31
#pragma unroll
        for (int r = 0; r < 4; ++r){
            const int row = wr*32 + m*16 + lq*4 + r;
            ldsEH[row*33 + col] = acceH[m][r];
            ldsEV[row*33 + col] = acceV[m][r];
        }
    }
    __syncthreads();

    // ---- inline cell: 256 threads x 8 elems ----
    const int crow = tid >> 2, ch = (tid & 3) * 8;
    const int grow = brow + crow;
    const float gv = g[grow];
    const size_t gbase = (size_t)grow*H_DIM + h0 + ch;
    union U4 { float4 v; float s[4]; };
    U4 sv0, sv1, hv0, hv1;
    sv0.v = *(const float4*)&sstate[gbase];
    sv1.v = *(const float4*)&sstate[gbase + 4];
    if (mode == 1){
        hv0.v = *(const float4*)&Hv32[gbase];
        hv1.v = *(const float4*)&Hv32[gbase + 4];
    }
    U4 sn0, sn1, hn0, hn1;
    union { unsigned short u[8]; f16x8 v; } hh;
#pragma unroll
    for (int e = 0; e < 8; ++e){
        const int hc = ch + e;
        const float f_ = ldsG[crow*132 + hc];
        const float i_ = ldsG[crow*132 + 32 + hc];
        const float o_ = ldsG[crow*132 + 64 + hc];
        const float q_ = ldsG[crow*132 + 96 + hc];
        const float eh = ldsEH[crow*33 + hc];
        const float ev = ldsEV[crow*33 + hc];
        const float a1 = (mode == 0) ? eh : ev;
        const float a2 = (mode == 0) ? ev : eh;
        const float svo = (e < 4) ? sv0.s[e] : sv1.s[e-4];
        float s, hval;
        if (mode == 0){
            const float shat = tanhf((1.0f - gv)*a1 + gv*a2);
            s = shat + i_*q_ + (1.0f - gv)*(f_*svo);
            hval = o_ * tanhf(s);
        } else {
            const float shat = tanhf(a1 + gv*a2);
            s = shat + (1.0f - gv)*svo + gv*(f_*svo + i_*q_);
            const float hvo = (e < 4) ? hv0.s[e] : hv1.s[e-4];
            hval = (1.0f - gv)*hvo + gv*(o_*tanhf(s));
            if (e < 4) hn0.s[e] = hval; else hn1.s[e-4] = hval;
        }
        if (e < 4) sn0.s[e] = s; else sn1.s[e-4] = s;
        hh.u[e] = f2h(hval);
    }
    *(float4*)&sstate[gbase]     = sn0.v;
    *(float4*)&sstate[gbase + 4] = sn1.v;
    if (mode == 1){
        *(float4*)&Hv32[gbase]     = hn0.v;
        *(float4*)&Hv32[gbase + 4] = hn1.v;
    }
    *(f16x8*)&Hnew[gbase] = hh.v;
}

// ---------------------------------------------------------------------------
// Predict (32 rows per pblk), double-buffered staging (counted vmcnt).
// p0=leaky(H@W0+b0), p1=leaky(p0@W1+b1), val=sigmoid(dot(p1,Wf)+bf) (*gmul).
// LDS: buf b at lds + b*36864 (A 4KB @+0, B 32KB @+4096); ldsP at 73728;
// sums at 90112. ~90.6KB (predict kernels run at 1 block/CU).
// K-accumulation order identical to the r10-verified version.
// ---------------------------------------------------------------------------
__device__ __forceinline__ void predict_dev(
    int pblk, const unsigned short* __restrict__ Hh,
    const unsigned short* __restrict__ W0T, const float* __restrict__ b0,
    const unsigned short* __restrict__ W1T, const float* __restrict__ b1,
    const float* __restrict__ Wf, const float* __restrict__ bf_,
    float* gstate, const float* __restrict__ gmul, float* pred, char* lds)
{
    char*  ldsP = lds + 73728;            // [32][512B] p0 fp16 (swizzled)
    float* sums = (float*)(lds + 90112);  // [4][32]
    const int tid = threadIdx.x, lane = tid & 63, w = tid >> 6;
    const int lr = lane & 15, lq = lane >> 4;
    const int brow = pblk * 32;

    f32x4 acc0[2][4];
#pragma unroll
    for (int m = 0; m < 2; ++m)
#pragma unroll
        for (int n = 0; n < 4; ++n){ f32x4 z = {0.f,0.f,0.f,0.f}; acc0[m][n] = z; }

    // ---- p0: K=512, 8 slabs, double-buffered (9 loads/thread/slab) ----
    stage64<32>(Hh + (size_t)brow*H_DIM, H_DIM, lds);
    stage64<256>(W0T, H_DIM, lds + 4096);
    int cur = 0;
    for (int s = 0; s < 8; ++s){
        char* bufc = lds + cur*36864;
        if (s + 1 < 8){
            char* bufn = lds + (cur^1)*36864;
            stage64<32>(Hh + (size_t)brow*H_DIM + (s+1)*64, H_DIM, bufn);
            stage64<256>(W0T + (s+1)*64, H_DIM, bufn + 4096);
            asm volatile("s_waitcnt vmcnt(9)" ::: "memory");
        } else {
            asm volatile("s_waitcnt vmcnt(0)" ::: "memory");
        }
        __builtin_amdgcn_s_barrier();
        __builtin_amdgcn_sched_barrier(0);
#pragma unroll
        for (int kk = 0; kk < 2; ++kk){
            f16x8 a[2], b[4];
#pragma unroll
            for (int m = 0; m < 2; ++m) a[m] = ldsfragh(bufc, m*16 + lr, kk*4 + lq);
#pragma unroll
            for (int n = 0; n < 4; ++n) b[n] = ldsfragh(bufc + 4096, w*64 + n*16 + lr, kk*4 + lq);
#pragma unroll
            for (int m = 0; m < 2; ++m)
#pragma unroll
                for (int n = 0; n < 4; ++n)
                    acc0[m][n] = __builtin_amdgcn_mfma_f32_16x16x32_f16(a[m], b[n], acc0[m][n], 0,0,0);
        }
        __builtin_amdgcn_sched_barrier(0);
        __builtin_amdgcn_s_barrier();
        cur ^= 1;
    }

    // ---- p0 epilogue -> ldsP (swizzled), identical math/layout ----
#pragma unroll
    for (int m = 0; m < 2; ++m){
#pragma unroll
        for (int n = 0; n < 4; ++n){
            const int col = w*64 + n*16 + lr;
            const float bs = b0[col];
#pragma unroll
            for (int r = 0; r < 4; ++r){
                const int row = m*16 + lq*4 + r;
                float x = acc0[m][n][r] + bs;
                x = (x > 0.0f) ? x : ALPHA*x;
                *(unsigned short*)(ldsP + row*512 + ((((col >> 3)) ^ (row & 7)) << 4) + (col & 7)*2) = f2h(x);
            }
        }
    }
    __syncthreads();

    // ---- p1: K=256, 4 slabs, double-buffered B (4 loads/thread/slab) ----
    f32x4 accp[2][2];
#pragma unroll
    for (int m = 0; m < 2; ++m)
#pragma unroll
        for (int n = 0; n < 2; ++n){ f32x4 z = {0.f,0.f,0.f,0.f}; accp[m][n] = z; }

    stage64<128>(W1T, P0_DIM, lds + 4096);
    cur = 0;
    for (int s = 0; s < 4; ++s){
        char* bufc = lds + cur*36864;
        if (s + 1 < 4){
            char* bufn = lds + (cur^1)*36864;
            stage64<128>(W1T + (s+1)*64, P0_DIM, bufn + 4096);
            asm volatile("s_waitcnt vmcnt(4)" ::: "memory");
        } else {
            asm volatile("s_waitcnt vmcnt(0)" ::: "memory");
        }
        __builtin_amdgcn_s_barrier();
        __builtin_amdgcn_sched_barrier(0);
#pragma unroll
        for (int kk = 0; kk < 2; ++kk){
            f16x8 a[2], b[2];
#pragma unroll
            for (int m = 0; m < 2; ++m){
                const int row = m*16 + lr;
                const int slot = s*8 + kk*4 + lq;
                a[m] = *(const f16x8*)(ldsP + row*512 + ((slot ^ (row & 7)) << 4));
            }
#pragma unroll
            for (int n = 0; n < 2; ++n) b[n] = ldsfragh(bufc + 4096, w*32 + n*16 + lr, kk*4 + lq);
#pragma unroll
            for (int m = 0; m < 2; ++m)
#pragma unroll
                for (int n = 0; n < 2; ++n)
                    accp[m][n] = __builtin_amdgcn_mfma_f32_16x16x32_f16(a[m], b[n], accp[m][n], 0,0,0);
        }
        __builtin_amdgcn_sched_barrier(0);
        __builtin_amdgcn_s_barrier();
        cur ^= 1;
    }

    // ---- head ----
    float part[8];
#pragma unroll
    for (int j = 0; j < 8; ++j) part[j] = 0.0f;
#pragma unroll
    for (int m = 0; m < 2; ++m){
#pragma unroll
        for (int n = 0; n < 2; ++n){
            const int col = w*32 + n*16 + lr;
            const float bs = b1[col], wf = Wf[col];
#pragma unroll
            for (int r = 0; r < 4; ++r){
                float x = accp[m][n][r] + bs;
                x = (x > 0.0f) ? x : ALPHA*x;
                part[m*4 + r] += x * wf;
            }
        }
    }
#pragma unroll
    for (int mask = 1; mask < 16; mask <<= 1)
#pragma unroll
        for (int j = 0; j < 8; ++j) part[j] += __shfl_xor(part[j], mask);
    if (lr == 0){
#pragma unroll
        for (int j = 0; j < 8; ++j){
            const int row = (j >> 2)*16 + lq*4 + (j & 3);
            sums[w*32 + row] = part[j];
        }
    }
    __syncthreads();
    if (tid < 32){
        float tot = sums[tid] + sums[32 + tid] + sums[64 + tid] + sums[96 + tid] + bf_[0];
        float val = sigmoidf_(tot);
        const int rowg = brow + tid;
        if (gmul)   val *= gmul[rowg];
        if (gstate) gstate[rowg] = val;
        if (pred)   pred[rowg]   = val;
    }
}

// x-step fp16 convert: 128 blocks x 256 thr x 4 float4.
__device__ __forceinline__ void xcvt_dev(int blk, const float* __restrict__ x,
                                         unsigned short* __restrict__ oh)
{
    const int tid = threadIdx.x;
#pragma unroll
    for (int j = 0; j < 4; ++j){
        const int t = blk*256 + tid + j*32768;
        float4 v = ((const float4*)x)[t];
        ushort4 h;
        h.x = f2h(v.x); h.y = f2h(v.y); h.z = f2h(v.z); h.w = f2h(v.w);
        ((ushort4*)oh)[t] = h;
    }
}

// ---------------------------------------------------------------------------
// LB: [0,64) predict_c (writes gnew, pred_c) | [64,128) predict_v(t-1) reads gold
//     | [128,256) xcvt(t+1)
// ---------------------------------------------------------------------------
__global__ __launch_bounds__(256) void k_LB(
    const unsigned short* __restrict__ Hcn,
    const unsigned short* __restrict__ Wp0Tc, const float* __restrict__ bpc0,
    const unsigned short* __restrict__ Wp1Tc, const float* __restrict__ bpc1,
    const float* __restrict__ Wfcc, const float* __restrict__ bfcc,
    float* __restrict__ gnew, float* __restrict__ predc,
    const unsigned short* __restrict__ Hvb,
    const unsigned short* __restrict__ Wp0Tv, const float* __restrict__ bpv0,
    const unsigned short* __restrict__ Wp1Tv, const float* __restrict__ bpv1,
    const float* __restrict__ Wfcv, const float* __restrict__ bfcv,
    const float* __restrict__ gold, float* __restrict__ predv,
    const float* __restrict__ xnext, unsigned short* __restrict__ Xnh)
{
    __shared__ __align__(16) char lds[90624];
    const int id = blockIdx.x;
    if (id < 64){
        predict_dev(id, Hcn, Wp0Tc, bpc0, Wp1Tc, bpc1, Wfcc, bfcc,
                    gnew, nullptr, predc, lds);
    } else if (id < 128){
        if (predv) predict_dev(id - 64, Hvb, Wp0Tv, bpv0, Wp1Tv, bpv1, Wfcv, bfcv,
                               nullptr, gold, predv, lds);
    } else {
        if (Xnh) xcvt_dev(id - 128, xnext, Xnh);
    }
}

// ---------------------------------------------------------------------------
// Standalone predict (init g0 / final pred_v) and x0 convert.
// ---------------------------------------------------------------------------
__global__ __launch_bounds__(256) void k_predict_g(
    const unsigned short* __restrict__ Hh,
    const unsigned short* __restrict__ W0T, const float* __restrict__ b0,
    const unsigned short* __restrict__ W1T, const float* __restrict__ b1,
    const float* __restrict__ Wf, const float* __restrict__ bf_,
    float* gstate, const float* __restrict__ gmul, float* pred)
{
    __shared__ __align__(16) char lds[90624];
    predict_dev(blockIdx.x, Hh, W0T, b0, W1T, b1, Wf, bf_, gstate, gmul, pred, lds);
}

__global__ __launch_bounds__(256) void k_xcvt_g(const float* __restrict__ x,
                                                unsigned short* __restrict__ oh)
{
    xcvt_dev(blockIdx.x, x, oh);
}

// ---------------------------------------------------------------------------
// Prep kernels. WT2 layout: n' = (h/32)*128 + z*32 + (h%32), k in [0,768).
// ---------------------------------------------------------------------------
__global__ __launch_bounds__(256) void k_wcat(const float* __restrict__ Wx,
                                              const float* __restrict__ Wh,
                                              unsigned short* __restrict__ oh){
    const int n = blockIdx.y;                 // n' in [0,2048)
    const int k = blockIdx.x*256 + threadIdx.x;
    const int z = (n >> 5) & 3;
    const int h = ((n >> 7) << 5) | (n & 31);
    float v = (k < 256) ? Wx[((size_t)z*E_DIM + k)*H_DIM + h]
                        : Wh[((size_t)z*H_DIM + (k - 256))*H_DIM + h];
    oh[(size_t)n*768 + k] = f2h(v);
}

__global__ __launch_bounds__(256) void k_trans(const float* __restrict__ in,
                                               unsigned short* __restrict__ oh,
                                               int K, int N){
    const int k = blockIdx.x*256 + threadIdx.x;
    const int n = blockIdx.y;
    if (k < K) oh[(size_t)n*K + k] = f2h(in[(size_t)k*N + n]);
}

__global__ __launch_bounds__(256) void k_init(float* __restrict__ sc, float* __restrict__ sv,
                                              float* __restrict__ hv32,
                                              unsigned short* __restrict__ hc0,
                                              unsigned short* __restrict__ hv0){
    const int i = blockIdx.x*256 + threadIdx.x;
    sc[i] = 0.0f; sv[i] = 0.0f; hv32[i] = 0.0f;
    hc0[i] = 0; hv0[i] = 0;
}

// ---------------------------------------------------------------------------
extern "C" void kernel_launch(void* const* d_in, const int* in_sizes, int n_in,
                              void* d_out, int out_size, void* d_ws, size_t ws_size,
                              hipStream_t stream)
{
    (void)in_sizes; (void)n_in; (void)out_size; (void)ws_size;

    const float* inputs = (const float*)d_in[0];
    const float* Wx_c   = (const float*)d_in[1];
    const float* bx_c   = (const float*)d_in[2];
    const float* Wh_c   = (const float*)d_in[3];
    const float* Wx_v   = (const float*)d_in[4];
    const float* bx_v   = (const float*)d_in[5];
    const float* Wh_v   = (const float*)d_in[6];
    const float* Ws     = (const float*)d_in[7];
    const float* Wpc0   = (const float*)d_in[8];
    const float* bpc0   = (const float*)d_in[9];
    const float* Wpc1   = (const float*)d_in[10];
    const float* bpc1   = (const float*)d_in[11];
    const float* Wfcc   = (const float*)d_in[12];
    const float* bfcc   = (const float*)d_in[13];
    const float* Wpv0   = (const float*)d_in[14];
    const float* bpv0   = (const float*)d_in[15];
    const float* Wpv1   = (const float*)d_in[16];
    const float* bpv1   = (const float*)d_in[17];
    const float* Wfcv   = (const float*)d_in[18];
    const float* bfcv   = (const float*)d_in[19];
    float* out = (float*)d_out;

    char* ws = (char*)d_ws;
    size_t off = 0;
    auto allocB = [&](size_t bytes) -> char* {
        char* p = ws + off;
        off = (off + bytes + 255) & ~(size_t)255;
        return p;
    };
    const size_t BH = (size_t)BATCH * H_DIM;
    const size_t BE = (size_t)BATCH * E_DIM;

    unsigned short* Xh[2];
    Xh[0] = (unsigned short*)allocB(BE*2);
    Xh[1] = (unsigned short*)allocB(BE*2);
    unsigned short* WT2c  = (unsigned short*)allocB((size_t)2048*768*2);
    unsigned short* WT2v  = (unsigned short*)allocB((size_t)2048*768*2);
    unsigned short* WsT   = (unsigned short*)allocB((size_t)4*H_DIM*H_DIM*2);
    unsigned short* Wp0Tc = (unsigned short*)allocB((size_t)P0_DIM*H_DIM*2);
    unsigned short* Wp0Tv = (unsigned short*)allocB((size_t)P0_DIM*H_DIM*2);
    unsigned short* Wp1Tc = (unsigned short*)allocB((size_t)P1_DIM*P0_DIM*2);
    unsigned short* Wp1Tv = (unsigned short*)allocB((size_t)P1_DIM*P0_DIM*2);
    unsigned short* Hc[2], *Hv[2];
    Hc[0] = (unsigned short*)allocB(BH*2);
    Hc[1] = (unsigned short*)allocB(BH*2);
    Hv[0] = (unsigned short*)allocB(BH*2);
    Hv[1] = (unsigned short*)allocB(BH*2);
    float* sc    = (float*)allocB(BH*4);
    float* sv    = (float*)allocB(BH*4);
    float* hv32  = (float*)allocB(BH*4);
    float* gbuf[2];
    gbuf[0] = (float*)allocB(BATCH*4);
    gbuf[1] = (float*)allocB(BATCH*4);

    const dim3 thr(256);
    const size_t HH = (size_t)H_DIM * H_DIM;

    // ---- one-time weight conversion ----
    k_wcat<<<dim3(3, 2048), thr, 0, stream>>>(Wx_c, Wh_c, WT2c);
    k_wcat<<<dim3(3, 2048), thr, 0, stream>>>(Wx_v, Wh_v, WT2v);
    for (int i = 0; i < 4; ++i)
        k_trans<<<dim3(2, 512), thr, 0, stream>>>(Ws + i*HH, WsT + i*HH, H_DIM, H_DIM);
    k_trans<<<dim3(2, 256), thr, 0, stream>>>(Wpc0, Wp0Tc, H_DIM, P0_DIM);
    k_trans<<<dim3(2, 256), thr, 0, stream>>>(Wpv0, Wp0Tv, H_DIM, P0_DIM);
    k_trans<<<dim3(1, 128), thr, 0, stream>>>(Wpc1, Wp1Tc, P0_DIM, P1_DIM);
    k_trans<<<dim3(1, 128), thr, 0, stream>>>(Wpv1, Wp1Tv, P0_DIM, P1_DIM);

    // ---- init: zero states; g0 = predict_c(zeros) -> gbuf[0]; convert x(0) ----
    k_init<<<4096, thr, 0, stream>>>(sc, sv, hv32, Hc[0], Hv[0]);
    k_predict_g<<<64, thr, 0, stream>>>(Hc[0], Wp0Tc, bpc0, Wp1Tc, bpc1, Wfcc, bfcc,
                                        gbuf[0], nullptr, nullptr);
    k_xcvt_g<<<128, thr, 0, stream>>>(inputs, Xh[0]);

    for (int t = 0; t < T_STEPS; ++t){
        const int cur = t & 1, nxt = cur ^ 1;

        // LA: fused click stream (gates_c + a1 + a2 + cell_c)
        k_fused<<<512, thr, 0, stream>>>(Xh[cur], Hc[cur], Hv[cur],
                                         WT2c, bx_c,
                                         WsT + 0*HH,   // Ws0 -> extraH = a1
                                         WsT + 1*HH,   // Ws1 -> extraV = a2
                                         gbuf[cur], sc, nullptr, Hc[nxt], 0);

        // LB: predict_c (g_new) + predict_v(t-1) (g_old) + xcvt(t+1)
        k_LB<<<256, thr, 0, stream>>>(Hc[nxt], Wp0Tc, bpc0, Wp1Tc, bpc1, Wfcc, bfcc,
                                      gbuf[nxt], out + (size_t)t*BATCH,
                                      Hv[cur], Wp0Tv, bpv0, Wp1Tv, bpv1, Wfcv, bfcv,
                                      gbuf[cur],
                                      (t > 0) ? out + (size_t)(T_STEPS + t - 1)*BATCH
                                              : nullptr,
                                      inputs + (size_t)(t+1)*BE,
                                      (t + 1 < T_STEPS) ? Xh[nxt] : nullptr);

        // LC: fused conversion stream (gates_v + a2v + a1v + cell_v)
        k_fused<<<512, thr, 0, stream>>>(Xh[cur], Hc[nxt], Hv[cur],
                                         WT2v, bx_v,
                                         WsT + 3*HH,   // Ws3 -> extraH = a2v
                                         WsT + 2*HH,   // Ws2 -> extraV = a1v
                                         gbuf[nxt], sv, hv32, Hv[nxt], 1);
    }
    // tail: pred_v(T-1); Hv_new(199)=Hv[0], g_new(199)=gbuf[0]
    k_predict_g<<<64, thr, 0, stream>>>(Hv[0], Wp0Tv, bpv0, Wp1Tv, bpv1, Wfcv, bfcv,
                                        nullptr, gbuf[0],
                                        out + (size_t)(2*T_STEPS - 1)*BATCH);
}